// Round 1
// baseline (255.473 us; speedup 1.0000x reference)
//
#include <hip/hip_runtime.h>
#include <hip/hip_bf16.h>

typedef __hip_bfloat16 bf16;
typedef __attribute__((ext_vector_type(8))) short short8;
typedef __attribute__((ext_vector_type(4))) short short4v;
typedef __attribute__((ext_vector_type(4))) float floatx4;

#define MFMA16 __builtin_amdgcn_mfma_f32_16x16x32_bf16

// ---------------------------------------------------------------------------
// B=2, S=2048, E=1024, H=16, D=64; M = 4096.  fp32 I/O, bf16 MFMA internal.
// R6 post-mortem: attn_k 73.7us, MfmaUtil 19%, HBM 3.6% -> latency-bound;
// staging fully serial (stage->barrier->compute), P path 16 scalar b16
// writes (4-way conflicts, 1.05M cycles) + 16 exp muls + 16 lpart adds.
// R7: (a) 2-phase double-buffered gl16 staging in qkv/attn/outproj (T3 min
// recipe: issue tile t+1 before computing tile t, one barrier per tile);
// (b) swapped QK^T (mfma(K,Q) -> S^T) so P packs to 4x ds_write_b64 via
// cvt_pk; (c) row-sum via ones-MFMA (accL), deletes lpart adds + shuffle
// reduce; (d) Q pre-scaled by 0.125*log2e, exp2 directly.
// ---------------------------------------------------------------------------

__device__ __forceinline__ void gl16(const void* g, void* l) {
    __builtin_amdgcn_global_load_lds(
        (const __attribute__((address_space(1))) void*)g,
        (__attribute__((address_space(3))) void*)l, 16, 0, 0);
}

// 4x fused 1024x1024 transpose + fp32->bf16: Wt[z][n][k] = (bf16)W[z][k][n]
__global__ __launch_bounds__(256) void wtrans_k(const float* __restrict__ w0,
                                                const float* __restrict__ w1,
                                                const float* __restrict__ w2,
                                                const float* __restrict__ w3,
                                                bf16* __restrict__ dst) {
    const float* srcs[4] = {w0, w1, w2, w3};
    const float* src = srcs[blockIdx.z];
    bf16* d = dst + (size_t)blockIdx.z * 1024 * 1024;
    __shared__ float t[32][33];
    int tx = threadIdx.x, ty = threadIdx.y;  // (32, 8)
    int x0 = blockIdx.x * 32, y0 = blockIdx.y * 32;
#pragma unroll
    for (int i = 0; i < 4; i++)
        t[ty + i * 8][tx] = src[(size_t)(y0 + ty + i * 8) * 1024 + x0 + tx];
    __syncthreads();
#pragma unroll
    for (int i = 0; i < 4; i++)
        d[(size_t)(x0 + ty + i * 8) * 1024 + y0 + tx] =
            __float2bfloat16(t[tx][ty + i * 8]);
}

// Fused QKV projection, 128x128 tiles, BK=32, 2-phase double-buffered.
// Grid (32 m, 8 n, 3 z).  A fp32 staged via global_load_lds (swizzle
// c^=r&7, 8 chunks/row); B bf16 staged likewise (c^=(r>>1)&3, 4 chunks/row).
// z=0: Q*(log2e/8) -> [B,H,S,D]; z=1: K -> [B,H,S,D]; z=2: V -> [B,H,D,S].
__global__ __launch_bounds__(256) void qkv_k(const float* __restrict__ xq,
                                             const float* __restrict__ xk,
                                             const float* __restrict__ xv,
                                             const bf16* __restrict__ wt,
                                             const float* __restrict__ bq,
                                             const float* __restrict__ bk,
                                             const float* __restrict__ bv,
                                             bf16* __restrict__ Qw,
                                             bf16* __restrict__ Kw,
                                             bf16* __restrict__ Vt) {
    __shared__ __align__(16) float lAf[2][128 * 32];  // 2x16 KB, swizzled
    __shared__ __align__(16) bf16 lB[2][128 * 32];    // 2x8 KB, swizzled
    int z = blockIdx.z;
    const float* A = (z == 0) ? xq : (z == 1) ? xk : xv;
    const bf16* Bt = wt + (size_t)z * (1024 * 1024);
    const float* bias = (z == 0) ? bq : (z == 1) ? bk : bv;
    int m0 = blockIdx.x * 128, n0 = blockIdx.y * 128;
    int tid = threadIdx.x, wave = tid >> 6, lane = tid & 63;
    int lm = lane & 15, quad = lane >> 4;
    int wm = wave >> 1, wn = wave & 1;
    int s7 = lm & 7;
    int swb = quad ^ ((lm >> 1) & 3);

    floatx4 acc[4][4];
#pragma unroll
    for (int i = 0; i < 4; i++)
#pragma unroll
        for (int j = 0; j < 4; j++) acc[i][j] = (floatx4){0.f, 0.f, 0.f, 0.f};

    auto stage = [&](int bufi, int kt) {
        // A fp32 tile: 1024 16B-slots, 4 instrs/wave; slot(r,cl), c = cl^(r&7)
#pragma unroll
        for (int q2 = 0; q2 < 4; q2++) {
            int slot0 = wave * 256 + q2 * 64;
            int r = (slot0 + lane) >> 3;
            int c = (lane & 7) ^ (r & 7);
            gl16(&A[(size_t)(m0 + r) * 1024 + kt * 32 + c * 4],
                 &lAf[bufi][slot0 * 4]);
        }
        // B bf16 tile: 512 slots, 2 instrs/wave; slot(r,cl), c = cl^((r>>1)&3)
#pragma unroll
        for (int q2 = 0; q2 < 2; q2++) {
            int slot0 = wave * 128 + q2 * 64;
            int r = (slot0 + lane) >> 2;
            int c = (lane & 3) ^ ((r >> 1) & 3);
            gl16(&Bt[(size_t)(n0 + r) * 1024 + kt * 32 + c * 8],
                 &lB[bufi][slot0 * 8]);
        }
    };

    stage(0, 0);
    __syncthreads();

    for (int kt = 0; kt < 32; kt++) {
        int cur = kt & 1;
        if (kt < 31) stage(cur ^ 1, kt + 1);  // prefetch flies under compute

        short8 af[4], bfr[4];
#pragma unroll
        for (int ms = 0; ms < 4; ms++) {
            int r = wm * 64 + ms * 16 + lm;  // (r&7)==s7
            float4 a0 = *(const float4*)&lAf[cur][(r * 8 + ((2 * quad) ^ s7)) * 4];
            float4 a1 = *(const float4*)&lAf[cur][(r * 8 + ((2 * quad + 1) ^ s7)) * 4];
            union { __hip_bfloat162 h2[4]; short8 s; } pk;
            pk.h2[0] = __float22bfloat162_rn(make_float2(a0.x, a0.y));
            pk.h2[1] = __float22bfloat162_rn(make_float2(a0.z, a0.w));
            pk.h2[2] = __float22bfloat162_rn(make_float2(a1.x, a1.y));
            pk.h2[3] = __float22bfloat162_rn(make_float2(a1.z, a1.w));
            af[ms] = pk.s;
        }
#pragma unroll
        for (int ns = 0; ns < 4; ns++) {
            int r = wn * 64 + ns * 16 + lm;  // ((r>>1)&3)==(lm>>1)&3
            bfr[ns] = *(const short8*)&lB[cur][(r * 4 + swb) * 8];
        }
#pragma unroll
        for (int ms = 0; ms < 4; ms++)
#pragma unroll
            for (int ns = 0; ns < 4; ns++)
                acc[ms][ns] = MFMA16(af[ms], bfr[ns], acc[ms][ns], 0, 0, 0);
        __syncthreads();
    }

    bf16* dstQK = (z == 0) ? Qw : Kw;
    float scale = (z == 0) ? 0.125f * 1.44269504f : 1.0f;  // fold log2e for exp2
#pragma unroll
    for (int ms = 0; ms < 4; ms++) {
        int rowb = m0 + wm * 64 + ms * 16 + quad * 4;
        int bb = rowb >> 11, s0 = rowb & 2047;
#pragma unroll
        for (int ns = 0; ns < 4; ns++) {
            int col = n0 + wn * 64 + ns * 16 + lm;
            float bvv = bias[col];
            int hh = col >> 6, d = col & 63;
            if (z < 2) {
#pragma unroll
                for (int rr = 0; rr < 4; rr++) {
                    float v = (acc[ms][ns][rr] + bvv) * scale;
                    dstQK[((((size_t)bb * 16 + hh) * 2048 + s0 + rr) << 6) + d] =
                        __float2bfloat16(v);
                }
            } else {
                short4v pk;
#pragma unroll
                for (int rr = 0; rr < 4; rr++) {
                    bf16 h = __float2bfloat16(acc[ms][ns][rr] + bvv);
                    pk[rr] = *(short*)&h;
                }
                *(short4v*)&Vt[((((size_t)bb * 16 + hh) * 64 + d) << 11) + s0] = pk;
            }
        }
    }
}

// Output projection: ctx[4096][1024] bf16 @ Wo^T + bo -> fp32.  128x64 tiles,
// grid (32 m, 16 n), 2-phase double-buffered staging.
__global__ __launch_bounds__(256) void outproj_k(const bf16* __restrict__ ctx,
                                                 const bf16* __restrict__ wot,
                                                 const float* __restrict__ bo,
                                                 float* __restrict__ out) {
    __shared__ __align__(16) bf16 lA[2][128 * 32];
    __shared__ __align__(16) bf16 lB[2][64 * 32];
    int m0 = blockIdx.x * 128, n0 = blockIdx.y * 64;
    int tid = threadIdx.x, wave = tid >> 6, lane = tid & 63;
    int lm = lane & 15, quad = lane >> 4;
    int wm = wave >> 1, wn = wave & 1;
    int swb = quad ^ ((lm >> 1) & 3);

    floatx4 acc[4][2];
#pragma unroll
    for (int i = 0; i < 4; i++)
#pragma unroll
        for (int j = 0; j < 2; j++) acc[i][j] = (floatx4){0.f, 0.f, 0.f, 0.f};

    auto stage = [&](int bufi, int kt) {
#pragma unroll
        for (int q2 = 0; q2 < 2; q2++) {
            int slot0 = wave * 128 + q2 * 64;
            int r = (slot0 + lane) >> 2;
            int c = (lane & 3) ^ ((r >> 1) & 3);
            gl16(&ctx[(size_t)(m0 + r) * 1024 + kt * 32 + c * 8],
                 &lA[bufi][slot0 * 8]);
        }
        {
            int slot0 = wave * 64;
            int r = (slot0 + lane) >> 2;
            int c = (lane & 3) ^ ((r >> 1) & 3);
            gl16(&wot[(size_t)(n0 + r) * 1024 + kt * 32 + c * 8],
                 &lB[bufi][slot0 * 8]);
        }
    };

    stage(0, 0);
    __syncthreads();

    for (int kt = 0; kt < 32; kt++) {
        int cur = kt & 1;
        if (kt < 31) stage(cur ^ 1, kt + 1);

        short8 af[4], bfr[2];
#pragma unroll
        for (int ms = 0; ms < 4; ms++) {
            int r = wm * 64 + ms * 16 + lm;
            af[ms] = *(const short8*)&lA[cur][(r * 4 + swb) * 8];
        }
#pragma unroll
        for (int ns = 0; ns < 2; ns++) {
            int r = wn * 32 + ns * 16 + lm;
            bfr[ns] = *(const short8*)&lB[cur][(r * 4 + swb) * 8];
        }
#pragma unroll
        for (int ms = 0; ms < 4; ms++)
#pragma unroll
            for (int ns = 0; ns < 2; ns++)
                acc[ms][ns] = MFMA16(af[ms], bfr[ns], acc[ms][ns], 0, 0, 0);
        __syncthreads();
    }

#pragma unroll
    for (int ms = 0; ms < 4; ms++) {
        int rowb = m0 + wm * 64 + ms * 16 + quad * 4;
#pragma unroll
        for (int ns = 0; ns < 2; ns++) {
            int col = n0 + wn * 32 + ns * 16 + lm;
            float bvv = bo[col];
#pragma unroll
            for (int rr = 0; rr < 4; rr++)
                out[(size_t)(rowb + rr) * 1024 + col] = acc[ms][ns][rr] + bvv;
        }
    }
}

// Flash attention, max-free softmax (|s| << 80), 2-phase double-buffered K/V.
// Q,K: [B,H,S,D] (Q pre-scaled by 0.125*log2e); Vt: [B,H,D,S].
// Grid (32 bh, 32 qtile), 256 thr.  Swapped QK^T: s = mfma(K,Q) = S^T, so
// each lane holds q=lm, k=16ns+4quad+rr (contiguous in rr) -> cvt_pk pairs,
// single ds_write_b64 per ns into XOR-swizzled lP[q][k] (wave-private rows).
// Row-sums via ones-MFMA: accL = mfma(P, 1s) -> every col = sum_k P[q,k],
// same row layout as o, no shuffle reduce.
__global__ __launch_bounds__(256) void attn_k(const bf16* __restrict__ Q,
                                              const bf16* __restrict__ K,
                                              const bf16* __restrict__ Vt,
                                              bf16* __restrict__ ctx) {
    __shared__ __align__(16) bf16 lK[2][64 * 64];  // swizzled, 2x8 KB
    __shared__ __align__(16) bf16 lV[2][64 * 64];  // swizzled, 2x8 KB
    __shared__ __align__(16) bf16 lP[64 * 64];     // swizzled, wave-private rows
    int bh = blockIdx.x, qt = blockIdx.y;
    int b = bh >> 4, h = bh & 15;
    const bf16* Qh = Q + (size_t)bh * (2048 * 64);
    const bf16* Kh = K + (size_t)bh * (2048 * 64);
    const bf16* Vh = Vt + (size_t)bh * (64 * 2048);
    int tid = threadIdx.x, wave = tid >> 6, lane = tid & 63;
    int lm = lane & 15, quad = lane >> 4;
    int s7 = lm & 7;

    int qrow = qt * 64 + wave * 16 + lm;
    short8 qf0 = *(const short8*)&Qh[(size_t)qrow * 64 + quad * 8];
    short8 qf1 = *(const short8*)&Qh[(size_t)qrow * 64 + 32 + quad * 8];

    short8 onesf;
#pragma unroll
    for (int i = 0; i < 8; i++) onesf[i] = (short)0x3F80;  // bf16 1.0

    floatx4 o[4];
#pragma unroll
    for (int i = 0; i < 4; i++) o[i] = (floatx4){0.f, 0.f, 0.f, 0.f};
    floatx4 accL = (floatx4){0.f, 0.f, 0.f, 0.f};

    auto stage = [&](int bufi, int kt) {
        // K (64 rows x 8 chunks) and V (64 d-rows x 8 chunks), c ^= r&7
#pragma unroll
        for (int q2 = 0; q2 < 2; q2++) {
            int slot0 = wave * 128 + q2 * 64;
            int r = (slot0 + lane) >> 3;
            int c = (lane & 7) ^ (r & 7);
            gl16(&Kh[(size_t)(kt * 64 + r) * 64 + c * 8], &lK[bufi][slot0 * 8]);
            gl16(&Vh[(size_t)r * 2048 + kt * 64 + c * 8], &lV[bufi][slot0 * 8]);
        }
    };

    stage(0, 0);
    __syncthreads();

    char* lProw = (char*)lP + (wave * 16 + lm) * 128;

    for (int kt = 0; kt < 32; kt++) {
        int cur = kt & 1;
        if (kt < 31) stage(cur ^ 1, kt + 1);  // prefetch under compute

        // S^T = K * Q^T : rows k, cols q
        floatx4 s[4];
#pragma unroll
        for (int i = 0; i < 4; i++) s[i] = (floatx4){0.f, 0.f, 0.f, 0.f};
#pragma unroll
        for (int ns = 0; ns < 4; ns++) {
            int r = ns * 16 + lm;  // (r&7)==s7
            short8 kf0 = *(const short8*)&lK[cur][(r * 8 + (quad ^ s7)) * 8];
            short8 kf1 = *(const short8*)&lK[cur][(r * 8 + ((4 + quad) ^ s7)) * 8];
            s[ns] = MFMA16(kf0, qf0, s[ns], 0, 0, 0);
            s[ns] = MFMA16(kf1, qf1, s[ns], 0, 0, 0);
        }

        // p = exp2(s) (log2e folded into Q); pack pairs; one b64 write per ns.
        // lane holds q=lm, k = 16ns + 4quad + rr; chunk=k>>3, swizzle ^ (q&7)
#pragma unroll
        for (int ns = 0; ns < 4; ns++) {
            float p0 = __builtin_amdgcn_exp2f(s[ns][0]);
            float p1 = __builtin_amdgcn_exp2f(s[ns][1]);
            float p2 = __builtin_amdgcn_exp2f(s[ns][2]);
            float p3 = __builtin_amdgcn_exp2f(s[ns][3]);
            union { __hip_bfloat162 h2[2]; short4v s4; } pk;
            pk.h2[0] = __float22bfloat162_rn(make_float2(p0, p1));
            pk.h2[1] = __float22bfloat162_rn(make_float2(p2, p3));
            int sw = (2 * ns + (quad >> 1)) ^ s7;
            *(short4v*)(lProw + sw * 16 + (quad & 1) * 8) = pk.s4;
        }
        // no barrier: lP rows are wave-private, LDS ops in-order per wave

        // O += P * V;  accL += P * 1s (row sums)
#pragma unroll
        for (int kk = 0; kk < 2; kk++) {
            int c2 = (kk * 4 + quad) ^ s7;
            short8 pf = *(const short8*)(lProw + c2 * 16);
            accL = MFMA16(pf, onesf, accL, 0, 0, 0);
#pragma unroll
            for (int ns = 0; ns < 4; ns++) {
                int r = ns * 16 + lm;
                short8 vf = *(const short8*)&lV[cur][(r * 8 + ((kk * 4 + quad) ^ s7)) * 8];
                o[ns] = MFMA16(pf, vf, o[ns], 0, 0, 0);
            }
        }
        __syncthreads();
    }

    float inv[4];
#pragma unroll
    for (int rr = 0; rr < 4; rr++) inv[rr] = 1.f / accL[rr];

#pragma unroll
    for (int ns = 0; ns < 4; ns++) {
        int e = h * 64 + ns * 16 + lm;
#pragma unroll
        for (int rr = 0; rr < 4; rr++) {
            int srow = qt * 64 + wave * 16 + quad * 4 + rr;
            ctx[(size_t)(b * 2048 + srow) * 1024 + e] =
                __float2bfloat16(o[ns][rr] * inv[rr]);
        }
    }
}

extern "C" void kernel_launch(void* const* d_in, const int* in_sizes, int n_in,
                              void* d_out, int out_size, void* d_ws, size_t ws_size,
                              hipStream_t stream) {
    const float* xv = (const float*)d_in[0];
    const float* xk = (const float*)d_in[1];
    const float* xq = (const float*)d_in[2];
    const float* Wq = (const float*)d_in[3];
    const float* bq = (const float*)d_in[4];
    const float* Wk = (const float*)d_in[5];
    const float* bk = (const float*)d_in[6];
    const float* Wv = (const float*)d_in[7];
    const float* bv = (const float*)d_in[8];
    const float* Wo = (const float*)d_in[9];
    const float* bo = (const float*)d_in[10];
    float* out = (float*)d_out;
    bf16* ws = (bf16*)d_ws;

    const size_t MB1 = 1024 * 1024;
    bf16* wt  = ws;             // 4 transposed bf16 weights (q,k,v,o)
    bf16* Qw  = ws + 4 * MB1;   // [B,H,S,D], pre-scaled by log2e/8
    bf16* Kw  = ws + 8 * MB1;   // [B,H,S,D]
    bf16* Vt  = ws + 12 * MB1;  // [B,H,D,S]
    bf16* ctx = ws + 16 * MB1;  // [B,S,E]   (total 40 MB)

    hipLaunchKernelGGL(wtrans_k, dim3(32, 32, 4), dim3(32, 8), 0, stream,
                       Wq, Wk, Wv, Wo, wt);

    hipLaunchKernelGGL(qkv_k, dim3(32, 8, 3), dim3(256), 0, stream,
                       xq, xk, xv, wt, bq, bk, bv, Qw, Kw, Vt);

    hipLaunchKernelGGL(attn_k, dim3(32, 32), dim3(256), 0, stream, Qw, Kw, Vt, ctx);

    hipLaunchKernelGGL(outproj_k, dim3(32, 16), dim3(256), 0, stream,
                       ctx, wt + 3 * MB1, bo, out);
}

// Round 2
// 235.069 us; speedup vs baseline: 1.0868x; 1.0868x over previous
//
#include <hip/hip_runtime.h>
#include <hip/hip_bf16.h>

typedef __hip_bfloat16 bf16;
typedef __attribute__((ext_vector_type(8))) short short8;
typedef __attribute__((ext_vector_type(4))) short short4v;
typedef __attribute__((ext_vector_type(4))) float floatx4;

#define MFMA16 __builtin_amdgcn_mfma_f32_16x16x32_bf16

// ---------------------------------------------------------------------------
// B=2, S=2048, E=1024, H=16, D=64; M = 4096.  fp32 I/O, bf16 MFMA internal.
// R7 post-mortem: qkv_k regressed to 82us (now top kernel): MfmaUtil 12%,
// VALU 32% -> fp32-A repack path (8 float4 LDS reads + 16 cvt_pk per
// wave-iter, A re-converted 16x) dominates; 48KB LDS.  attn_k improved
// (dropped out of top-5).
// R8: pre-cast xq/xk/xv to bf16 once (xcast_k, ~12us mem-bound), qkv_k
// becomes pure bf16 GEMM with A staged identically to B (4 gl16/wave-iter,
// 32KB LDS, ds_read_b128 fragments, zero repack VALU).  attn/outproj kept.
// ---------------------------------------------------------------------------

__device__ __forceinline__ void gl16(const void* g, void* l) {
    __builtin_amdgcn_global_load_lds(
        (const __attribute__((address_space(1))) void*)g,
        (__attribute__((address_space(3))) void*)l, 16, 0, 0);
}

// 4x fused 1024x1024 transpose + fp32->bf16: Wt[z][n][k] = (bf16)W[z][k][n]
__global__ __launch_bounds__(256) void wtrans_k(const float* __restrict__ w0,
                                                const float* __restrict__ w1,
                                                const float* __restrict__ w2,
                                                const float* __restrict__ w3,
                                                bf16* __restrict__ dst) {
    const float* srcs[4] = {w0, w1, w2, w3};
    const float* src = srcs[blockIdx.z];
    bf16* d = dst + (size_t)blockIdx.z * 1024 * 1024;
    __shared__ float t[32][33];
    int tx = threadIdx.x, ty = threadIdx.y;  // (32, 8)
    int x0 = blockIdx.x * 32, y0 = blockIdx.y * 32;
#pragma unroll
    for (int i = 0; i < 4; i++)
        t[ty + i * 8][tx] = src[(size_t)(y0 + ty + i * 8) * 1024 + x0 + tx];
    __syncthreads();
#pragma unroll
    for (int i = 0; i < 4; i++)
        d[(size_t)(x0 + ty + i * 8) * 1024 + y0 + tx] =
            __float2bfloat16(t[tx][ty + i * 8]);
}

// fp32 -> bf16 cast of the three activation tensors, 8 elems/thread.
// Grid (2048, 3) x 256 thr: 2048*256*8 = 4096*1024 elems per tensor exactly.
__global__ __launch_bounds__(256) void xcast_k(const float* __restrict__ x0,
                                               const float* __restrict__ x1,
                                               const float* __restrict__ x2,
                                               bf16* __restrict__ dst) {
    const float* srcs[3] = {x0, x1, x2};
    const float* src = srcs[blockIdx.y];
    bf16* d = dst + (size_t)blockIdx.y * (4096 * 1024);
    size_t i = (size_t)blockIdx.x * 256 + threadIdx.x;  // 8-elem chunk index
    const float4* s4 = (const float4*)src + i * 2;
    float4 a = s4[0], b = s4[1];
    union { __hip_bfloat162 h2[4]; short8 s; } pk;
    pk.h2[0] = __float22bfloat162_rn(make_float2(a.x, a.y));
    pk.h2[1] = __float22bfloat162_rn(make_float2(a.z, a.w));
    pk.h2[2] = __float22bfloat162_rn(make_float2(b.x, b.y));
    pk.h2[3] = __float22bfloat162_rn(make_float2(b.z, b.w));
    *(short8*)&d[i * 8] = pk.s;
}

// Fused QKV projection, pure bf16, 128x128 tiles, BK=32, 2-phase dbuf.
// Grid (32 m, 8 n, 3 z).  A,B both staged via global_load_lds, swizzle
// c = cl ^ ((r>>1)&3), 4 chunks/row.  z=0: Q*(log2e/8) -> [B,H,S,D];
// z=1: K -> [B,H,S,D]; z=2: V -> [B,H,D,S].
__global__ __launch_bounds__(256) void qkv_k(const bf16* __restrict__ xb,
                                             const bf16* __restrict__ wt,
                                             const float* __restrict__ bq,
                                             const float* __restrict__ bk,
                                             const float* __restrict__ bv,
                                             bf16* __restrict__ Qw,
                                             bf16* __restrict__ Kw,
                                             bf16* __restrict__ Vt) {
    __shared__ __align__(16) bf16 lA[2][128 * 32];  // 2x8 KB, swizzled
    __shared__ __align__(16) bf16 lB[2][128 * 32];  // 2x8 KB, swizzled
    int z = blockIdx.z;
    const bf16* A = xb + (size_t)z * (4096 * 1024);
    const bf16* Bt = wt + (size_t)z * (1024 * 1024);
    const float* bias = (z == 0) ? bq : (z == 1) ? bk : bv;
    int m0 = blockIdx.x * 128, n0 = blockIdx.y * 128;
    int tid = threadIdx.x, wave = tid >> 6, lane = tid & 63;
    int lm = lane & 15, quad = lane >> 4;
    int wm = wave >> 1, wn = wave & 1;
    int swb = quad ^ ((lm >> 1) & 3);

    floatx4 acc[4][4];
#pragma unroll
    for (int i = 0; i < 4; i++)
#pragma unroll
        for (int j = 0; j < 4; j++) acc[i][j] = (floatx4){0.f, 0.f, 0.f, 0.f};

    auto stage = [&](int bufi, int kt) {
        // A and B bf16 tiles: 512 slots each, 2 gl16/wave each
#pragma unroll
        for (int q2 = 0; q2 < 2; q2++) {
            int slot0 = wave * 128 + q2 * 64;
            int r = (slot0 + lane) >> 2;
            int c = (lane & 3) ^ ((r >> 1) & 3);
            gl16(&A[(size_t)(m0 + r) * 1024 + kt * 32 + c * 8],
                 &lA[bufi][slot0 * 8]);
            gl16(&Bt[(size_t)(n0 + r) * 1024 + kt * 32 + c * 8],
                 &lB[bufi][slot0 * 8]);
        }
    };

    stage(0, 0);
    __syncthreads();

    for (int kt = 0; kt < 32; kt++) {
        int cur = kt & 1;
        if (kt < 31) stage(cur ^ 1, kt + 1);  // prefetch flies under compute

        short8 af[4], bfr[4];
#pragma unroll
        for (int ms = 0; ms < 4; ms++) {
            int r = wm * 64 + ms * 16 + lm;  // ((r>>1)&3)==(lm>>1)&3
            af[ms] = *(const short8*)&lA[cur][(r * 4 + swb) * 8];
        }
#pragma unroll
        for (int ns = 0; ns < 4; ns++) {
            int r = wn * 64 + ns * 16 + lm;
            bfr[ns] = *(const short8*)&lB[cur][(r * 4 + swb) * 8];
        }
#pragma unroll
        for (int ms = 0; ms < 4; ms++)
#pragma unroll
            for (int ns = 0; ns < 4; ns++)
                acc[ms][ns] = MFMA16(af[ms], bfr[ns], acc[ms][ns], 0, 0, 0);
        __syncthreads();
    }

    bf16* dstQK = (z == 0) ? Qw : Kw;
    float scale = (z == 0) ? 0.125f * 1.44269504f : 1.0f;  // fold log2e for exp2
#pragma unroll
    for (int ms = 0; ms < 4; ms++) {
        int rowb = m0 + wm * 64 + ms * 16 + quad * 4;
        int bb = rowb >> 11, s0 = rowb & 2047;
#pragma unroll
        for (int ns = 0; ns < 4; ns++) {
            int col = n0 + wn * 64 + ns * 16 + lm;
            float bvv = bias[col];
            int hh = col >> 6, d = col & 63;
            if (z < 2) {
#pragma unroll
                for (int rr = 0; rr < 4; rr++) {
                    float v = (acc[ms][ns][rr] + bvv) * scale;
                    dstQK[((((size_t)bb * 16 + hh) * 2048 + s0 + rr) << 6) + d] =
                        __float2bfloat16(v);
                }
            } else {
                short4v pk;
#pragma unroll
                for (int rr = 0; rr < 4; rr++) {
                    bf16 h = __float2bfloat16(acc[ms][ns][rr] + bvv);
                    pk[rr] = *(short*)&h;
                }
                *(short4v*)&Vt[((((size_t)bb * 16 + hh) * 64 + d) << 11) + s0] = pk;
            }
        }
    }
}

// Output projection: ctx[4096][1024] bf16 @ Wo^T + bo -> fp32.  128x64 tiles,
// grid (32 m, 16 n), 2-phase double-buffered staging.
__global__ __launch_bounds__(256) void outproj_k(const bf16* __restrict__ ctx,
                                                 const bf16* __restrict__ wot,
                                                 const float* __restrict__ bo,
                                                 float* __restrict__ out) {
    __shared__ __align__(16) bf16 lA[2][128 * 32];
    __shared__ __align__(16) bf16 lB[2][64 * 32];
    int m0 = blockIdx.x * 128, n0 = blockIdx.y * 64;
    int tid = threadIdx.x, wave = tid >> 6, lane = tid & 63;
    int lm = lane & 15, quad = lane >> 4;
    int wm = wave >> 1, wn = wave & 1;
    int swb = quad ^ ((lm >> 1) & 3);

    floatx4 acc[4][2];
#pragma unroll
    for (int i = 0; i < 4; i++)
#pragma unroll
        for (int j = 0; j < 2; j++) acc[i][j] = (floatx4){0.f, 0.f, 0.f, 0.f};

    auto stage = [&](int bufi, int kt) {
#pragma unroll
        for (int q2 = 0; q2 < 2; q2++) {
            int slot0 = wave * 128 + q2 * 64;
            int r = (slot0 + lane) >> 2;
            int c = (lane & 3) ^ ((r >> 1) & 3);
            gl16(&ctx[(size_t)(m0 + r) * 1024 + kt * 32 + c * 8],
                 &lA[bufi][slot0 * 8]);
        }
        {
            int slot0 = wave * 64;
            int r = (slot0 + lane) >> 2;
            int c = (lane & 3) ^ ((r >> 1) & 3);
            gl16(&wot[(size_t)(n0 + r) * 1024 + kt * 32 + c * 8],
                 &lB[bufi][slot0 * 8]);
        }
    };

    stage(0, 0);
    __syncthreads();

    for (int kt = 0; kt < 32; kt++) {
        int cur = kt & 1;
        if (kt < 31) stage(cur ^ 1, kt + 1);

        short8 af[4], bfr[2];
#pragma unroll
        for (int ms = 0; ms < 4; ms++) {
            int r = wm * 64 + ms * 16 + lm;
            af[ms] = *(const short8*)&lA[cur][(r * 4 + swb) * 8];
        }
#pragma unroll
        for (int ns = 0; ns < 2; ns++) {
            int r = wn * 32 + ns * 16 + lm;
            bfr[ns] = *(const short8*)&lB[cur][(r * 4 + swb) * 8];
        }
#pragma unroll
        for (int ms = 0; ms < 4; ms++)
#pragma unroll
            for (int ns = 0; ns < 2; ns++)
                acc[ms][ns] = MFMA16(af[ms], bfr[ns], acc[ms][ns], 0, 0, 0);
        __syncthreads();
    }

#pragma unroll
    for (int ms = 0; ms < 4; ms++) {
        int rowb = m0 + wm * 64 + ms * 16 + quad * 4;
#pragma unroll
        for (int ns = 0; ns < 2; ns++) {
            int col = n0 + wn * 32 + ns * 16 + lm;
            float bvv = bo[col];
#pragma unroll
            for (int rr = 0; rr < 4; rr++)
                out[(size_t)(rowb + rr) * 1024 + col] = acc[ms][ns][rr] + bvv;
        }
    }
}

// Flash attention, max-free softmax (|s| << 80), 2-phase double-buffered K/V.
// Q,K: [B,H,S,D] (Q pre-scaled by 0.125*log2e); Vt: [B,H,D,S].
// Grid (32 bh, 32 qtile), 256 thr.  Swapped QK^T: s = mfma(K,Q) = S^T, so
// each lane holds q=lm, k=16ns+4quad+rr (contiguous in rr) -> cvt_pk pairs,
// single ds_write_b64 per ns into XOR-swizzled lP[q][k] (wave-private rows).
// Row-sums via ones-MFMA: accL = mfma(P, 1s) -> every col = sum_k P[q,k],
// same row layout as o, no shuffle reduce.
__global__ __launch_bounds__(256) void attn_k(const bf16* __restrict__ Q,
                                              const bf16* __restrict__ K,
                                              const bf16* __restrict__ Vt,
                                              bf16* __restrict__ ctx) {
    __shared__ __align__(16) bf16 lK[2][64 * 64];  // swizzled, 2x8 KB
    __shared__ __align__(16) bf16 lV[2][64 * 64];  // swizzled, 2x8 KB
    __shared__ __align__(16) bf16 lP[64 * 64];     // swizzled, wave-private rows
    int bh = blockIdx.x, qt = blockIdx.y;
    int b = bh >> 4, h = bh & 15;
    const bf16* Qh = Q + (size_t)bh * (2048 * 64);
    const bf16* Kh = K + (size_t)bh * (2048 * 64);
    const bf16* Vh = Vt + (size_t)bh * (64 * 2048);
    int tid = threadIdx.x, wave = tid >> 6, lane = tid & 63;
    int lm = lane & 15, quad = lane >> 4;
    int s7 = lm & 7;

    int qrow = qt * 64 + wave * 16 + lm;
    short8 qf0 = *(const short8*)&Qh[(size_t)qrow * 64 + quad * 8];
    short8 qf1 = *(const short8*)&Qh[(size_t)qrow * 64 + 32 + quad * 8];

    short8 onesf;
#pragma unroll
    for (int i = 0; i < 8; i++) onesf[i] = (short)0x3F80;  // bf16 1.0

    floatx4 o[4];
#pragma unroll
    for (int i = 0; i < 4; i++) o[i] = (floatx4){0.f, 0.f, 0.f, 0.f};
    floatx4 accL = (floatx4){0.f, 0.f, 0.f, 0.f};

    auto stage = [&](int bufi, int kt) {
        // K (64 rows x 8 chunks) and V (64 d-rows x 8 chunks), c ^= r&7
#pragma unroll
        for (int q2 = 0; q2 < 2; q2++) {
            int slot0 = wave * 128 + q2 * 64;
            int r = (slot0 + lane) >> 3;
            int c = (lane & 7) ^ (r & 7);
            gl16(&Kh[(size_t)(kt * 64 + r) * 64 + c * 8], &lK[bufi][slot0 * 8]);
            gl16(&Vh[(size_t)r * 2048 + kt * 64 + c * 8], &lV[bufi][slot0 * 8]);
        }
    };

    stage(0, 0);
    __syncthreads();

    char* lProw = (char*)lP + (wave * 16 + lm) * 128;

    for (int kt = 0; kt < 32; kt++) {
        int cur = kt & 1;
        if (kt < 31) stage(cur ^ 1, kt + 1);  // prefetch under compute

        // S^T = K * Q^T : rows k, cols q
        floatx4 s[4];
#pragma unroll
        for (int i = 0; i < 4; i++) s[i] = (floatx4){0.f, 0.f, 0.f, 0.f};
#pragma unroll
        for (int ns = 0; ns < 4; ns++) {
            int r = ns * 16 + lm;  // (r&7)==s7
            short8 kf0 = *(const short8*)&lK[cur][(r * 8 + (quad ^ s7)) * 8];
            short8 kf1 = *(const short8*)&lK[cur][(r * 8 + ((4 + quad) ^ s7)) * 8];
            s[ns] = MFMA16(kf0, qf0, s[ns], 0, 0, 0);
            s[ns] = MFMA16(kf1, qf1, s[ns], 0, 0, 0);
        }

        // p = exp2(s) (log2e folded into Q); pack pairs; one b64 write per ns.
        // lane holds q=lm, k = 16ns + 4quad + rr; chunk=k>>3, swizzle ^ (q&7)
#pragma unroll
        for (int ns = 0; ns < 4; ns++) {
            float p0 = __builtin_amdgcn_exp2f(s[ns][0]);
            float p1 = __builtin_amdgcn_exp2f(s[ns][1]);
            float p2 = __builtin_amdgcn_exp2f(s[ns][2]);
            float p3 = __builtin_amdgcn_exp2f(s[ns][3]);
            union { __hip_bfloat162 h2[2]; short4v s4; } pk;
            pk.h2[0] = __float22bfloat162_rn(make_float2(p0, p1));
            pk.h2[1] = __float22bfloat162_rn(make_float2(p2, p3));
            int sw = (2 * ns + (quad >> 1)) ^ s7;
            *(short4v*)(lProw + sw * 16 + (quad & 1) * 8) = pk.s4;
        }
        // no barrier: lP rows are wave-private, LDS ops in-order per wave

        // O += P * V;  accL += P * 1s (row sums)
#pragma unroll
        for (int kk = 0; kk < 2; kk++) {
            int c2 = (kk * 4 + quad) ^ s7;
            short8 pf = *(const short8*)(lProw + c2 * 16);
            accL = MFMA16(pf, onesf, accL, 0, 0, 0);
#pragma unroll
            for (int ns = 0; ns < 4; ns++) {
                int r = ns * 16 + lm;
                short8 vf = *(const short8*)&lV[cur][(r * 8 + ((kk * 4 + quad) ^ s7)) * 8];
                o[ns] = MFMA16(pf, vf, o[ns], 0, 0, 0);
            }
        }
        __syncthreads();
    }

    float inv[4];
#pragma unroll
    for (int rr = 0; rr < 4; rr++) inv[rr] = 1.f / accL[rr];

#pragma unroll
    for (int ns = 0; ns < 4; ns++) {
        int e = h * 64 + ns * 16 + lm;
#pragma unroll
        for (int rr = 0; rr < 4; rr++) {
            int srow = qt * 64 + wave * 16 + quad * 4 + rr;
            ctx[(size_t)(b * 2048 + srow) * 1024 + e] =
                __float2bfloat16(o[ns][rr] * inv[rr]);
        }
    }
}

extern "C" void kernel_launch(void* const* d_in, const int* in_sizes, int n_in,
                              void* d_out, int out_size, void* d_ws, size_t ws_size,
                              hipStream_t stream) {
    const float* xv = (const float*)d_in[0];
    const float* xk = (const float*)d_in[1];
    const float* xq = (const float*)d_in[2];
    const float* Wq = (const float*)d_in[3];
    const float* bq = (const float*)d_in[4];
    const float* Wk = (const float*)d_in[5];
    const float* bk = (const float*)d_in[6];
    const float* Wv = (const float*)d_in[7];
    const float* bv = (const float*)d_in[8];
    const float* Wo = (const float*)d_in[9];
    const float* bo = (const float*)d_in[10];
    float* out = (float*)d_out;
    bf16* ws = (bf16*)d_ws;

    const size_t MB1 = 1024 * 1024;
    bf16* wt  = ws;              // 4 transposed bf16 weights (q,k,v,o)
    bf16* Qw  = ws + 4 * MB1;    // [B,H,S,D], pre-scaled by log2e/8
    bf16* Kw  = ws + 8 * MB1;    // [B,H,S,D]
    bf16* Vt  = ws + 12 * MB1;   // [B,H,D,S]
    bf16* ctx = ws + 16 * MB1;   // [B,S,E]
    bf16* xb  = ws + 20 * MB1;   // 3 bf16 activation tensors (q,k,v) (total 64 MB)

    hipLaunchKernelGGL(wtrans_k, dim3(32, 32, 4), dim3(32, 8), 0, stream,
                       Wq, Wk, Wv, Wo, wt);

    hipLaunchKernelGGL(xcast_k, dim3(2048, 3), dim3(256), 0, stream,
                       xq, xk, xv, xb);

    hipLaunchKernelGGL(qkv_k, dim3(32, 8, 3), dim3(256), 0, stream,
                       xb, wt, bq, bk, bv, Qw, Kw, Vt);

    hipLaunchKernelGGL(attn_k, dim3(32, 32), dim3(256), 0, stream, Qw, Kw, Vt, ctx);

    hipLaunchKernelGGL(outproj_k, dim3(32, 16), dim3(256), 0, stream,
                       ctx, wt + 3 * MB1, bo, out);
}

// Round 3
// 228.119 us; speedup vs baseline: 1.1199x; 1.0305x over previous
//
#include <hip/hip_runtime.h>
#include <hip/hip_bf16.h>

typedef __hip_bfloat16 bf16;
typedef __attribute__((ext_vector_type(8))) short short8;
typedef __attribute__((ext_vector_type(4))) short short4v;
typedef __attribute__((ext_vector_type(4))) float floatx4;

#define MFMA16 __builtin_amdgcn_mfma_f32_16x16x32_bf16
#define BARRIER __builtin_amdgcn_s_barrier
#define SCHEDB0() __builtin_amdgcn_sched_barrier(0)

// ---------------------------------------------------------------------------
// B=2, S=2048, E=1024, H=16, D=64; M = 4096.  fp32 I/O, bf16 MFMA internal.
// R8 post-mortem: attn_k 64.4us top kernel, MfmaUtil 24%, ~1200cy wall per
// wave-iter vs ~300cy issue -> the __syncthreads() at end of each k-tile
// forces compiler vmcnt(0) drain of the just-issued prefetch (m97-structure
// stall).  Bank conflicts (16cy/wave-iter) are the free 2-way b128 alias.
// R9: T4 counted-vmcnt + raw s_barrier schedule in qkv/attn/outproj:
//   barrier1 (reads done) -> stage(kt+1) -> vmcnt(4) -> barrier2 -> compute
// Prefetch never drains to 0 in the main loop (m218 recipe, +38-73% there).
// ---------------------------------------------------------------------------

__device__ __forceinline__ void gl16(const void* g, void* l) {
    __builtin_amdgcn_global_load_lds(
        (const __attribute__((address_space(1))) void*)g,
        (__attribute__((address_space(3))) void*)l, 16, 0, 0);
}

// 4x fused 1024x1024 transpose + fp32->bf16: Wt[z][n][k] = (bf16)W[z][k][n]
__global__ __launch_bounds__(256) void wtrans_k(const float* __restrict__ w0,
                                                const float* __restrict__ w1,
                                                const float* __restrict__ w2,
                                                const float* __restrict__ w3,
                                                bf16* __restrict__ dst) {
    const float* srcs[4] = {w0, w1, w2, w3};
    const float* src = srcs[blockIdx.z];
    bf16* d = dst + (size_t)blockIdx.z * 1024 * 1024;
    __shared__ float t[32][33];
    int tx = threadIdx.x, ty = threadIdx.y;  // (32, 8)
    int x0 = blockIdx.x * 32, y0 = blockIdx.y * 32;
#pragma unroll
    for (int i = 0; i < 4; i++)
        t[ty + i * 8][tx] = src[(size_t)(y0 + ty + i * 8) * 1024 + x0 + tx];
    __syncthreads();
#pragma unroll
    for (int i = 0; i < 4; i++)
        d[(size_t)(x0 + ty + i * 8) * 1024 + y0 + tx] =
            __float2bfloat16(t[tx][ty + i * 8]);
}

// fp32 -> bf16 cast of the three activation tensors, 8 elems/thread.
// Grid (2048, 3) x 256 thr: 2048*256*8 = 4096*1024 elems per tensor exactly.
__global__ __launch_bounds__(256) void xcast_k(const float* __restrict__ x0,
                                               const float* __restrict__ x1,
                                               const float* __restrict__ x2,
                                               bf16* __restrict__ dst) {
    const float* srcs[3] = {x0, x1, x2};
    const float* src = srcs[blockIdx.y];
    bf16* d = dst + (size_t)blockIdx.y * (4096 * 1024);
    size_t i = (size_t)blockIdx.x * 256 + threadIdx.x;  // 8-elem chunk index
    const float4* s4 = (const float4*)src + i * 2;
    float4 a = s4[0], b = s4[1];
    union { __hip_bfloat162 h2[4]; short8 s; } pk;
    pk.h2[0] = __float22bfloat162_rn(make_float2(a.x, a.y));
    pk.h2[1] = __float22bfloat162_rn(make_float2(a.z, a.w));
    pk.h2[2] = __float22bfloat162_rn(make_float2(b.x, b.y));
    pk.h2[3] = __float22bfloat162_rn(make_float2(b.z, b.w));
    *(short8*)&d[i * 8] = pk.s;
}

// Fused QKV projection, pure bf16, 128x128 tiles, BK=32, counted-vmcnt dbuf.
// Grid (32 m, 8 n, 3 z).  A,B both staged via global_load_lds, swizzle
// c = cl ^ ((r>>1)&3), 4 chunks/row.  z=0: Q*(log2e/8) -> [B,H,S,D];
// z=1: K -> [B,H,S,D]; z=2: V -> [B,H,D,S].
__global__ __launch_bounds__(256) void qkv_k(const bf16* __restrict__ xb,
                                             const bf16* __restrict__ wt,
                                             const float* __restrict__ bq,
                                             const float* __restrict__ bk,
                                             const float* __restrict__ bv,
                                             bf16* __restrict__ Qw,
                                             bf16* __restrict__ Kw,
                                             bf16* __restrict__ Vt) {
    __shared__ __align__(16) bf16 lA[2][128 * 32];  // 2x8 KB, swizzled
    __shared__ __align__(16) bf16 lB[2][128 * 32];  // 2x8 KB, swizzled
    int z = blockIdx.z;
    const bf16* A = xb + (size_t)z * (4096 * 1024);
    const bf16* Bt = wt + (size_t)z * (1024 * 1024);
    const float* bias = (z == 0) ? bq : (z == 1) ? bk : bv;
    int m0 = blockIdx.x * 128, n0 = blockIdx.y * 128;
    int tid = threadIdx.x, wave = tid >> 6, lane = tid & 63;
    int lm = lane & 15, quad = lane >> 4;
    int wm = wave >> 1, wn = wave & 1;
    int swb = quad ^ ((lm >> 1) & 3);

    floatx4 acc[4][4];
#pragma unroll
    for (int i = 0; i < 4; i++)
#pragma unroll
        for (int j = 0; j < 4; j++) acc[i][j] = (floatx4){0.f, 0.f, 0.f, 0.f};

    auto stage = [&](int bufi, int kt) {
        // A and B bf16 tiles: 512 slots each, 2 gl16/wave each (4 loads total)
#pragma unroll
        for (int q2 = 0; q2 < 2; q2++) {
            int slot0 = wave * 128 + q2 * 64;
            int r = (slot0 + lane) >> 2;
            int c = (lane & 3) ^ ((r >> 1) & 3);
            gl16(&A[(size_t)(m0 + r) * 1024 + kt * 32 + c * 8],
                 &lA[bufi][slot0 * 8]);
            gl16(&Bt[(size_t)(n0 + r) * 1024 + kt * 32 + c * 8],
                 &lB[bufi][slot0 * 8]);
        }
    };

    auto compute = [&](int cur) {
        short8 af[4], bfr[4];
#pragma unroll
        for (int ms = 0; ms < 4; ms++) {
            int r = wm * 64 + ms * 16 + lm;  // ((r>>1)&3)==(lm>>1)&3
            af[ms] = *(const short8*)&lA[cur][(r * 4 + swb) * 8];
        }
#pragma unroll
        for (int ns = 0; ns < 4; ns++) {
            int r = wn * 64 + ns * 16 + lm;
            bfr[ns] = *(const short8*)&lB[cur][(r * 4 + swb) * 8];
        }
#pragma unroll
        for (int ms = 0; ms < 4; ms++)
#pragma unroll
            for (int ns = 0; ns < 4; ns++)
                acc[ms][ns] = MFMA16(af[ms], bfr[ns], acc[ms][ns], 0, 0, 0);
    };

    stage(0, 0);
    for (int kt = 0; kt < 31; kt++) {
        int cur = kt & 1;
        BARRIER();                      // all reads of buf cur^1 finished
        stage(cur ^ 1, kt + 1);         // 4 loads into buf cur^1
        asm volatile("s_waitcnt vmcnt(4)" ::: "memory");  // my tile-kt done
        BARRIER();                      // everyone's tile-kt loads done
        SCHEDB0();
        compute(cur);
    }
    BARRIER();
    asm volatile("s_waitcnt vmcnt(0)" ::: "memory");
    BARRIER();
    SCHEDB0();
    compute(1);  // kt=31, cur=1

    bf16* dstQK = (z == 0) ? Qw : Kw;
    float scale = (z == 0) ? 0.125f * 1.44269504f : 1.0f;  // fold log2e for exp2
#pragma unroll
    for (int ms = 0; ms < 4; ms++) {
        int rowb = m0 + wm * 64 + ms * 16 + quad * 4;
        int bb = rowb >> 11, s0 = rowb & 2047;
#pragma unroll
        for (int ns = 0; ns < 4; ns++) {
            int col = n0 + wn * 64 + ns * 16 + lm;
            float bvv = bias[col];
            int hh = col >> 6, d = col & 63;
            if (z < 2) {
#pragma unroll
                for (int rr = 0; rr < 4; rr++) {
                    float v = (acc[ms][ns][rr] + bvv) * scale;
                    dstQK[((((size_t)bb * 16 + hh) * 2048 + s0 + rr) << 6) + d] =
                        __float2bfloat16(v);
                }
            } else {
                short4v pk;
#pragma unroll
                for (int rr = 0; rr < 4; rr++) {
                    bf16 h = __float2bfloat16(acc[ms][ns][rr] + bvv);
                    pk[rr] = *(short*)&h;
                }
                *(short4v*)&Vt[((((size_t)bb * 16 + hh) * 64 + d) << 11) + s0] = pk;
            }
        }
    }
}

// Output projection: ctx[4096][1024] bf16 @ Wo^T + bo -> fp32.  128x64 tiles,
// grid (32 m, 16 n), counted-vmcnt double-buffered staging (3 loads/wave).
__global__ __launch_bounds__(256) void outproj_k(const bf16* __restrict__ ctx,
                                                 const bf16* __restrict__ wot,
                                                 const float* __restrict__ bo,
                                                 float* __restrict__ out) {
    __shared__ __align__(16) bf16 lA[2][128 * 32];
    __shared__ __align__(16) bf16 lB[2][64 * 32];
    int m0 = blockIdx.x * 128, n0 = blockIdx.y * 64;
    int tid = threadIdx.x, wave = tid >> 6, lane = tid & 63;
    int lm = lane & 15, quad = lane >> 4;
    int wm = wave >> 1, wn = wave & 1;
    int swb = quad ^ ((lm >> 1) & 3);

    floatx4 acc[4][2];
#pragma unroll
    for (int i = 0; i < 4; i++)
#pragma unroll
        for (int j = 0; j < 2; j++) acc[i][j] = (floatx4){0.f, 0.f, 0.f, 0.f};

    auto stage = [&](int bufi, int kt) {
#pragma unroll
        for (int q2 = 0; q2 < 2; q2++) {
            int slot0 = wave * 128 + q2 * 64;
            int r = (slot0 + lane) >> 2;
            int c = (lane & 3) ^ ((r >> 1) & 3);
            gl16(&ctx[(size_t)(m0 + r) * 1024 + kt * 32 + c * 8],
                 &lA[bufi][slot0 * 8]);
        }
        {
            int slot0 = wave * 64;
            int r = (slot0 + lane) >> 2;
            int c = (lane & 3) ^ ((r >> 1) & 3);
            gl16(&wot[(size_t)(n0 + r) * 1024 + kt * 32 + c * 8],
                 &lB[bufi][slot0 * 8]);
        }
    };

    auto compute = [&](int cur) {
        short8 af[4], bfr[2];
#pragma unroll
        for (int ms = 0; ms < 4; ms++) {
            int r = wm * 64 + ms * 16 + lm;
            af[ms] = *(const short8*)&lA[cur][(r * 4 + swb) * 8];
        }
#pragma unroll
        for (int ns = 0; ns < 2; ns++) {
            int r = wn * 32 + ns * 16 + lm;
            bfr[ns] = *(const short8*)&lB[cur][(r * 4 + swb) * 8];
        }
#pragma unroll
        for (int ms = 0; ms < 4; ms++)
#pragma unroll
            for (int ns = 0; ns < 2; ns++)
                acc[ms][ns] = MFMA16(af[ms], bfr[ns], acc[ms][ns], 0, 0, 0);
    };

    stage(0, 0);
    for (int kt = 0; kt < 31; kt++) {
        int cur = kt & 1;
        BARRIER();
        stage(cur ^ 1, kt + 1);  // 3 loads
        asm volatile("s_waitcnt vmcnt(3)" ::: "memory");
        BARRIER();
        SCHEDB0();
        compute(cur);
    }
    BARRIER();
    asm volatile("s_waitcnt vmcnt(0)" ::: "memory");
    BARRIER();
    SCHEDB0();
    compute(1);  // kt=31

#pragma unroll
    for (int ms = 0; ms < 4; ms++) {
        int rowb = m0 + wm * 64 + ms * 16 + quad * 4;
#pragma unroll
        for (int ns = 0; ns < 2; ns++) {
            int col = n0 + wn * 32 + ns * 16 + lm;
            float bvv = bo[col];
#pragma unroll
            for (int rr = 0; rr < 4; rr++)
                out[(size_t)(rowb + rr) * 1024 + col] = acc[ms][ns][rr] + bvv;
        }
    }
}

// Flash attention, max-free softmax (|s| << 80), counted-vmcnt dbuf K/V.
// Q,K: [B,H,S,D] (Q pre-scaled by 0.125*log2e); Vt: [B,H,D,S].
// Grid (32 bh, 32 qtile), 256 thr.  Swapped QK^T: s = mfma(K,Q) = S^T, so
// each lane holds q=lm, k=16ns+4quad+rr (contiguous in rr) -> cvt_pk pairs,
// single ds_write_b64 per ns into XOR-swizzled lP[q][k] (wave-private rows).
// Row-sums via ones-MFMA: accL = mfma(P, 1s).
__global__ __launch_bounds__(256) void attn_k(const bf16* __restrict__ Q,
                                              const bf16* __restrict__ K,
                                              const bf16* __restrict__ Vt,
                                              bf16* __restrict__ ctx) {
    __shared__ __align__(16) bf16 lK[2][64 * 64];  // swizzled, 2x8 KB
    __shared__ __align__(16) bf16 lV[2][64 * 64];  // swizzled, 2x8 KB
    __shared__ __align__(16) bf16 lP[64 * 64];     // swizzled, wave-private rows
    int bh = blockIdx.x, qt = blockIdx.y;
    int b = bh >> 4, h = bh & 15;
    const bf16* Qh = Q + (size_t)bh * (2048 * 64);
    const bf16* Kh = K + (size_t)bh * (2048 * 64);
    const bf16* Vh = Vt + (size_t)bh * (64 * 2048);
    int tid = threadIdx.x, wave = tid >> 6, lane = tid & 63;
    int lm = lane & 15, quad = lane >> 4;
    int s7 = lm & 7;

    int qrow = qt * 64 + wave * 16 + lm;
    short8 qf0 = *(const short8*)&Qh[(size_t)qrow * 64 + quad * 8];
    short8 qf1 = *(const short8*)&Qh[(size_t)qrow * 64 + 32 + quad * 8];

    short8 onesf;
#pragma unroll
    for (int i = 0; i < 8; i++) onesf[i] = (short)0x3F80;  // bf16 1.0

    floatx4 o[4];
#pragma unroll
    for (int i = 0; i < 4; i++) o[i] = (floatx4){0.f, 0.f, 0.f, 0.f};
    floatx4 accL = (floatx4){0.f, 0.f, 0.f, 0.f};

    auto stage = [&](int bufi, int kt) {
        // K (64 rows x 8 chunks) and V (64 d-rows x 8 chunks), c ^= r&7
#pragma unroll
        for (int q2 = 0; q2 < 2; q2++) {
            int slot0 = wave * 128 + q2 * 64;
            int r = (slot0 + lane) >> 3;
            int c = (lane & 7) ^ (r & 7);
            gl16(&Kh[(size_t)(kt * 64 + r) * 64 + c * 8], &lK[bufi][slot0 * 8]);
            gl16(&Vh[(size_t)r * 2048 + kt * 64 + c * 8], &lV[bufi][slot0 * 8]);
        }
    };

    char* lProw = (char*)lP + (wave * 16 + lm) * 128;

    auto compute = [&](int cur) {
        // S^T = K * Q^T : rows k, cols q
        floatx4 s[4];
#pragma unroll
        for (int i = 0; i < 4; i++) s[i] = (floatx4){0.f, 0.f, 0.f, 0.f};
#pragma unroll
        for (int ns = 0; ns < 4; ns++) {
            int r = ns * 16 + lm;  // (r&7)==s7
            short8 kf0 = *(const short8*)&lK[cur][(r * 8 + (quad ^ s7)) * 8];
            short8 kf1 = *(const short8*)&lK[cur][(r * 8 + ((4 + quad) ^ s7)) * 8];
            s[ns] = MFMA16(kf0, qf0, s[ns], 0, 0, 0);
            s[ns] = MFMA16(kf1, qf1, s[ns], 0, 0, 0);
        }

        // p = exp2(s) (log2e folded into Q); pack pairs; one b64 write per ns.
#pragma unroll
        for (int ns = 0; ns < 4; ns++) {
            float p0 = __builtin_amdgcn_exp2f(s[ns][0]);
            float p1 = __builtin_amdgcn_exp2f(s[ns][1]);
            float p2 = __builtin_amdgcn_exp2f(s[ns][2]);
            float p3 = __builtin_amdgcn_exp2f(s[ns][3]);
            union { __hip_bfloat162 h2[2]; short4v s4; } pk;
            pk.h2[0] = __float22bfloat162_rn(make_float2(p0, p1));
            pk.h2[1] = __float22bfloat162_rn(make_float2(p2, p3));
            int sw = (2 * ns + (quad >> 1)) ^ s7;
            *(short4v*)(lProw + sw * 16 + (quad & 1) * 8) = pk.s4;
        }
        // no barrier: lP rows are wave-private, LDS ops in-order per wave

        // O += P * V;  accL += P * 1s (row sums)
#pragma unroll
        for (int kk = 0; kk < 2; kk++) {
            int c2 = (kk * 4 + quad) ^ s7;
            short8 pf = *(const short8*)(lProw + c2 * 16);
            accL = MFMA16(pf, onesf, accL, 0, 0, 0);
#pragma unroll
            for (int ns = 0; ns < 4; ns++) {
                int r = ns * 16 + lm;
                short8 vf = *(const short8*)&lV[cur][(r * 8 + ((kk * 4 + quad) ^ s7)) * 8];
                o[ns] = MFMA16(pf, vf, o[ns], 0, 0, 0);
            }
        }
    };

    stage(0, 0);
    for (int kt = 0; kt < 31; kt++) {
        int cur = kt & 1;
        BARRIER();                      // all reads of buf cur^1 finished
        stage(cur ^ 1, kt + 1);         // 4 loads
        asm volatile("s_waitcnt vmcnt(4)" ::: "memory");
        BARRIER();                      // everyone's tile-kt loads done
        SCHEDB0();
        compute(cur);
    }
    BARRIER();
    asm volatile("s_waitcnt vmcnt(0)" ::: "memory");
    BARRIER();
    SCHEDB0();
    compute(1);  // kt=31

    float inv[4];
#pragma unroll
    for (int rr = 0; rr < 4; rr++) inv[rr] = 1.f / accL[rr];

#pragma unroll
    for (int ns = 0; ns < 4; ns++) {
        int e = h * 64 + ns * 16 + lm;
#pragma unroll
        for (int rr = 0; rr < 4; rr++) {
            int srow = qt * 64 + wave * 16 + quad * 4 + rr;
            ctx[(size_t)(b * 2048 + srow) * 1024 + e] =
                __float2bfloat16(o[ns][rr] * inv[rr]);
        }
    }
}

extern "C" void kernel_launch(void* const* d_in, const int* in_sizes, int n_in,
                              void* d_out, int out_size, void* d_ws, size_t ws_size,
                              hipStream_t stream) {
    const float* xv = (const float*)d_in[0];
    const float* xk = (const float*)d_in[1];
    const float* xq = (const float*)d_in[2];
    const float* Wq = (const float*)d_in[3];
    const float* bq = (const float*)d_in[4];
    const float* Wk = (const float*)d_in[5];
    const float* bk = (const float*)d_in[6];
    const float* Wv = (const float*)d_in[7];
    const float* bv = (const float*)d_in[8];
    const float* Wo = (const float*)d_in[9];
    const float* bo = (const float*)d_in[10];
    float* out = (float*)d_out;
    bf16* ws = (bf16*)d_ws;

    const size_t MB1 = 1024 * 1024;
    bf16* wt  = ws;              // 4 transposed bf16 weights (q,k,v,o)
    bf16* Qw  = ws + 4 * MB1;    // [B,H,S,D], pre-scaled by log2e/8
    bf16* Kw  = ws + 8 * MB1;    // [B,H,S,D]
    bf16* Vt  = ws + 12 * MB1;   // [B,H,D,S]
    bf16* ctx = ws + 16 * MB1;   // [B,S,E]
    bf16* xb  = ws + 20 * MB1;   // 3 bf16 activation tensors (q,k,v) (total 64 MB)

    hipLaunchKernelGGL(wtrans_k, dim3(32, 32, 4), dim3(32, 8), 0, stream,
                       Wq, Wk, Wv, Wo, wt);

    hipLaunchKernelGGL(xcast_k, dim3(2048, 3), dim3(256), 0, stream,
                       xq, xk, xv, xb);

    hipLaunchKernelGGL(qkv_k, dim3(32, 8, 3), dim3(256), 0, stream,
                       xb, wt, bq, bk, bv, Qw, Kw, Vt);

    hipLaunchKernelGGL(attn_k, dim3(32, 32), dim3(256), 0, stream, Qw, Kw, Vt, ctx);

    hipLaunchKernelGGL(outproj_k, dim3(32, 16), dim3(256), 0, stream,
                       ctx, wt + 3 * MB1, bo, out);
}

// Round 4
// 219.289 us; speedup vs baseline: 1.1650x; 1.0403x over previous
//
#include <hip/hip_runtime.h>
#include <hip/hip_bf16.h>

typedef __hip_bfloat16 bf16;
typedef __attribute__((ext_vector_type(8))) short short8;
typedef __attribute__((ext_vector_type(4))) short short4v;
typedef __attribute__((ext_vector_type(4))) float floatx4;

#define MFMA16 __builtin_amdgcn_mfma_f32_16x16x32_bf16
#define BARRIER __builtin_amdgcn_s_barrier
#define SCHEDB0() __builtin_amdgcn_sched_barrier(0)
#define SETPRIO __builtin_amdgcn_s_setprio

// ---------------------------------------------------------------------------
// B=2, S=2048, E=1024, H=16, D=64; M = 4096.  fp32 I/O, bf16 MFMA internal.
// R9 post-mortem: counted-vmcnt left attn flat -> NOT barrier-drain-bound.
// LDS-BW model: 96KB LDS traffic per block-iter x4 blocks/CU / 85B/cy ~=
// 4500cy ~= measured 4950cy/iter -> attn_k is LDS-bandwidth-bound, and
// 64KB of the 96KB is the SAME K/V fragments read by all 4 waves.
// R10: attn QBLK=128 (each wave owns 32 q rows, qh in {0,1}); kf/vf loads
// hoisted and shared across both q-halves -> LDS bytes/FLOP -42%; grid
// (32,16), 48KB LDS, 2 blocks/CU; + T5 setprio around MFMA clusters.
// qkv: depth-2 prefetch (3 buffers, 48KB, steady-state vmcnt(8)).
// ---------------------------------------------------------------------------

__device__ __forceinline__ void gl16(const void* g, void* l) {
    __builtin_amdgcn_global_load_lds(
        (const __attribute__((address_space(1))) void*)g,
        (__attribute__((address_space(3))) void*)l, 16, 0, 0);
}

// 4x fused 1024x1024 transpose + fp32->bf16: Wt[z][n][k] = (bf16)W[z][k][n]
__global__ __launch_bounds__(256) void wtrans_k(const float* __restrict__ w0,
                                                const float* __restrict__ w1,
                                                const float* __restrict__ w2,
                                                const float* __restrict__ w3,
                                                bf16* __restrict__ dst) {
    const float* srcs[4] = {w0, w1, w2, w3};
    const float* src = srcs[blockIdx.z];
    bf16* d = dst + (size_t)blockIdx.z * 1024 * 1024;
    __shared__ float t[32][33];
    int tx = threadIdx.x, ty = threadIdx.y;  // (32, 8)
    int x0 = blockIdx.x * 32, y0 = blockIdx.y * 32;
#pragma unroll
    for (int i = 0; i < 4; i++)
        t[ty + i * 8][tx] = src[(size_t)(y0 + ty + i * 8) * 1024 + x0 + tx];
    __syncthreads();
#pragma unroll
    for (int i = 0; i < 4; i++)
        d[(size_t)(x0 + ty + i * 8) * 1024 + y0 + tx] =
            __float2bfloat16(t[tx][ty + i * 8]);
}

// fp32 -> bf16 cast of the three activation tensors, 8 elems/thread.
__global__ __launch_bounds__(256) void xcast_k(const float* __restrict__ x0,
                                               const float* __restrict__ x1,
                                               const float* __restrict__ x2,
                                               bf16* __restrict__ dst) {
    const float* srcs[3] = {x0, x1, x2};
    const float* src = srcs[blockIdx.y];
    bf16* d = dst + (size_t)blockIdx.y * (4096 * 1024);
    size_t i = (size_t)blockIdx.x * 256 + threadIdx.x;  // 8-elem chunk index
    const float4* s4 = (const float4*)src + i * 2;
    float4 a = s4[0], b = s4[1];
    union { __hip_bfloat162 h2[4]; short8 s; } pk;
    pk.h2[0] = __float22bfloat162_rn(make_float2(a.x, a.y));
    pk.h2[1] = __float22bfloat162_rn(make_float2(a.z, a.w));
    pk.h2[2] = __float22bfloat162_rn(make_float2(b.x, b.y));
    pk.h2[3] = __float22bfloat162_rn(make_float2(b.z, b.w));
    *(short8*)&d[i * 8] = pk.s;
}

// Fused QKV projection, pure bf16, 128x128 tiles, BK=32, depth-2 prefetch
// (3 buffers, steady-state vmcnt(8): tiles kt+1,kt+2 in flight).
// Grid (32 m, 8 n, 3 z).  z=0: Q*(log2e/8); z=1: K; z=2: V -> [B,H,D,S].
__global__ __launch_bounds__(256) void qkv_k(const bf16* __restrict__ xb,
                                             const bf16* __restrict__ wt,
                                             const float* __restrict__ bq,
                                             const float* __restrict__ bk,
                                             const float* __restrict__ bv,
                                             bf16* __restrict__ Qw,
                                             bf16* __restrict__ Kw,
                                             bf16* __restrict__ Vt) {
    __shared__ __align__(16) bf16 lA[3][128 * 32];  // 3x8 KB, swizzled
    __shared__ __align__(16) bf16 lB[3][128 * 32];  // 3x8 KB, swizzled
    int z = blockIdx.z;
    const bf16* A = xb + (size_t)z * (4096 * 1024);
    const bf16* Bt = wt + (size_t)z * (1024 * 1024);
    const float* bias = (z == 0) ? bq : (z == 1) ? bk : bv;
    int m0 = blockIdx.x * 128, n0 = blockIdx.y * 128;
    int tid = threadIdx.x, wave = tid >> 6, lane = tid & 63;
    int lm = lane & 15, quad = lane >> 4;
    int wm = wave >> 1, wn = wave & 1;
    int swb = quad ^ ((lm >> 1) & 3);

    floatx4 acc[4][4];
#pragma unroll
    for (int i = 0; i < 4; i++)
#pragma unroll
        for (int j = 0; j < 4; j++) acc[i][j] = (floatx4){0.f, 0.f, 0.f, 0.f};

    auto stage = [&](int bufi, int kt) {
        // A and B bf16 tiles: 512 slots each, 2 gl16/wave each (4 loads total)
#pragma unroll
        for (int q2 = 0; q2 < 2; q2++) {
            int slot0 = wave * 128 + q2 * 64;
            int r = (slot0 + lane) >> 2;
            int c = (lane & 3) ^ ((r >> 1) & 3);
            gl16(&A[(size_t)(m0 + r) * 1024 + kt * 32 + c * 8],
                 &lA[bufi][slot0 * 8]);
            gl16(&Bt[(size_t)(n0 + r) * 1024 + kt * 32 + c * 8],
                 &lB[bufi][slot0 * 8]);
        }
    };

    auto compute = [&](int cur) {
        short8 af[4], bfr[4];
#pragma unroll
        for (int ms = 0; ms < 4; ms++) {
            int r = wm * 64 + ms * 16 + lm;  // ((r>>1)&3)==(lm>>1)&3
            af[ms] = *(const short8*)&lA[cur][(r * 4 + swb) * 8];
        }
#pragma unroll
        for (int ns = 0; ns < 4; ns++) {
            int r = wn * 64 + ns * 16 + lm;
            bfr[ns] = *(const short8*)&lB[cur][(r * 4 + swb) * 8];
        }
        SETPRIO(1);
#pragma unroll
        for (int ms = 0; ms < 4; ms++)
#pragma unroll
            for (int ns = 0; ns < 4; ns++)
                acc[ms][ns] = MFMA16(af[ms], bfr[ns], acc[ms][ns], 0, 0, 0);
        SETPRIO(0);
    };

    stage(0, 0);
    stage(1, 1);
    for (int kt = 0; kt < 32; kt++) {
        int cur = kt % 3;
        BARRIER();  // all reads of buf (kt+2)%3 (done at iter kt-1) finished
        if (kt < 30) {
            stage((kt + 2) % 3, kt + 2);
            asm volatile("s_waitcnt vmcnt(8)" ::: "memory");  // tile kt done
        } else if (kt == 30) {
            asm volatile("s_waitcnt vmcnt(4)" ::: "memory");
        } else {
            asm volatile("s_waitcnt vmcnt(0)" ::: "memory");
        }
        BARRIER();  // everyone's tile-kt loads done
        SCHEDB0();
        compute(cur);
    }

    bf16* dstQK = (z == 0) ? Qw : Kw;
    float scale = (z == 0) ? 0.125f * 1.44269504f : 1.0f;  // fold log2e for exp2
#pragma unroll
    for (int ms = 0; ms < 4; ms++) {
        int rowb = m0 + wm * 64 + ms * 16 + quad * 4;
        int bb = rowb >> 11, s0 = rowb & 2047;
#pragma unroll
        for (int ns = 0; ns < 4; ns++) {
            int col = n0 + wn * 64 + ns * 16 + lm;
            float bvv = bias[col];
            int hh = col >> 6, d = col & 63;
            if (z < 2) {
#pragma unroll
                for (int rr = 0; rr < 4; rr++) {
                    float v = (acc[ms][ns][rr] + bvv) * scale;
                    dstQK[((((size_t)bb * 16 + hh) * 2048 + s0 + rr) << 6) + d] =
                        __float2bfloat16(v);
                }
            } else {
                short4v pk;
#pragma unroll
                for (int rr = 0; rr < 4; rr++) {
                    bf16 h = __float2bfloat16(acc[ms][ns][rr] + bvv);
                    pk[rr] = *(short*)&h;
                }
                *(short4v*)&Vt[((((size_t)bb * 16 + hh) * 64 + d) << 11) + s0] = pk;
            }
        }
    }
}

// Output projection: ctx[4096][1024] bf16 @ Wo^T + bo -> fp32.  128x64 tiles,
// grid (32 m, 16 n), counted-vmcnt double-buffered staging (3 loads/wave).
__global__ __launch_bounds__(256) void outproj_k(const bf16* __restrict__ ctx,
                                                 const bf16* __restrict__ wot,
                                                 const float* __restrict__ bo,
                                                 float* __restrict__ out) {
    __shared__ __align__(16) bf16 lA[2][128 * 32];
    __shared__ __align__(16) bf16 lB[2][64 * 32];
    int m0 = blockIdx.x * 128, n0 = blockIdx.y * 64;
    int tid = threadIdx.x, wave = tid >> 6, lane = tid & 63;
    int lm = lane & 15, quad = lane >> 4;
    int wm = wave >> 1, wn = wave & 1;
    int swb = quad ^ ((lm >> 1) & 3);

    floatx4 acc[4][2];
#pragma unroll
    for (int i = 0; i < 4; i++)
#pragma unroll
        for (int j = 0; j < 2; j++) acc[i][j] = (floatx4){0.f, 0.f, 0.f, 0.f};

    auto stage = [&](int bufi, int kt) {
#pragma unroll
        for (int q2 = 0; q2 < 2; q2++) {
            int slot0 = wave * 128 + q2 * 64;
            int r = (slot0 + lane) >> 2;
            int c = (lane & 3) ^ ((r >> 1) & 3);
            gl16(&ctx[(size_t)(m0 + r) * 1024 + kt * 32 + c * 8],
                 &lA[bufi][slot0 * 8]);
        }
        {
            int slot0 = wave * 64;
            int r = (slot0 + lane) >> 2;
            int c = (lane & 3) ^ ((r >> 1) & 3);
            gl16(&wot[(size_t)(n0 + r) * 1024 + kt * 32 + c * 8],
                 &lB[bufi][slot0 * 8]);
        }
    };

    auto compute = [&](int cur) {
        short8 af[4], bfr[2];
#pragma unroll
        for (int ms = 0; ms < 4; ms++) {
            int r = wm * 64 + ms * 16 + lm;
            af[ms] = *(const short8*)&lA[cur][(r * 4 + swb) * 8];
        }
#pragma unroll
        for (int ns = 0; ns < 2; ns++) {
            int r = wn * 32 + ns * 16 + lm;
            bfr[ns] = *(const short8*)&lB[cur][(r * 4 + swb) * 8];
        }
        SETPRIO(1);
#pragma unroll
        for (int ms = 0; ms < 4; ms++)
#pragma unroll
            for (int ns = 0; ns < 2; ns++)
                acc[ms][ns] = MFMA16(af[ms], bfr[ns], acc[ms][ns], 0, 0, 0);
        SETPRIO(0);
    };

    stage(0, 0);
    for (int kt = 0; kt < 31; kt++) {
        int cur = kt & 1;
        BARRIER();
        stage(cur ^ 1, kt + 1);  // 3 loads
        asm volatile("s_waitcnt vmcnt(3)" ::: "memory");
        BARRIER();
        SCHEDB0();
        compute(cur);
    }
    BARRIER();
    asm volatile("s_waitcnt vmcnt(0)" ::: "memory");
    BARRIER();
    SCHEDB0();
    compute(1);  // kt=31

#pragma unroll
    for (int ms = 0; ms < 4; ms++) {
        int rowb = m0 + wm * 64 + ms * 16 + quad * 4;
#pragma unroll
        for (int ns = 0; ns < 2; ns++) {
            int col = n0 + wn * 32 + ns * 16 + lm;
            float bvv = bo[col];
#pragma unroll
            for (int rr = 0; rr < 4; rr++)
                out[(size_t)(rowb + rr) * 1024 + col] = acc[ms][ns][rr] + bvv;
        }
    }
}

// Flash attention, max-free softmax (|s| << 80), QBLK=128 / KVBLK=64.
// Q,K: [B,H,S,D] (Q pre-scaled by 0.125*log2e); Vt: [B,H,D,S].
// Grid (32 bh, 16 qtile), 256 thr, 48KB LDS (2 blocks/CU).
// Each wave owns 32 q rows (qh in {0,1}); shared kf/vf LDS reads are
// hoisted and reused for both q-halves (halves LDS bytes per FLOP — R10).
// Swapped QK^T: s = mfma(K, Q[qh]) = S^T; cvt_pk pairs -> one ds_write_b64
// per (qh,ns) into XOR-swizzled wave-private lP rows; row sums via
// ones-MFMA.
__global__ __launch_bounds__(256) void attn_k(const bf16* __restrict__ Q,
                                              const bf16* __restrict__ K,
                                              const bf16* __restrict__ Vt,
                                              bf16* __restrict__ ctx) {
    __shared__ __align__(16) bf16 lK[2][64 * 64];  // swizzled, 2x8 KB
    __shared__ __align__(16) bf16 lV[2][64 * 64];  // swizzled, 2x8 KB
    __shared__ __align__(16) bf16 lP[128 * 64];    // swizzled, wave-private rows
    int bh = blockIdx.x, qt = blockIdx.y;
    int b = bh >> 4, h = bh & 15;
    const bf16* Qh = Q + (size_t)bh * (2048 * 64);
    const bf16* Kh = K + (size_t)bh * (2048 * 64);
    const bf16* Vh = Vt + (size_t)bh * (64 * 2048);
    int tid = threadIdx.x, wave = tid >> 6, lane = tid & 63;
    int lm = lane & 15, quad = lane >> 4;
    int s7 = lm & 7;

    short8 qf[2][2];
#pragma unroll
    for (int qh = 0; qh < 2; qh++) {
        int qrow = qt * 128 + wave * 32 + qh * 16 + lm;
        qf[qh][0] = *(const short8*)&Qh[(size_t)qrow * 64 + quad * 8];
        qf[qh][1] = *(const short8*)&Qh[(size_t)qrow * 64 + 32 + quad * 8];
    }

    short8 onesf;
#pragma unroll
    for (int i = 0; i < 8; i++) onesf[i] = (short)0x3F80;  // bf16 1.0

    floatx4 o[2][4];
#pragma unroll
    for (int qh = 0; qh < 2; qh++)
#pragma unroll
        for (int i = 0; i < 4; i++) o[qh][i] = (floatx4){0.f, 0.f, 0.f, 0.f};
    floatx4 accL[2] = {(floatx4){0.f, 0.f, 0.f, 0.f},
                       (floatx4){0.f, 0.f, 0.f, 0.f}};

    auto stage = [&](int bufi, int kt) {
        // K (64 rows x 8 chunks) and V (64 d-rows x 8 chunks), c ^= r&7
#pragma unroll
        for (int q2 = 0; q2 < 2; q2++) {
            int slot0 = wave * 128 + q2 * 64;
            int r = (slot0 + lane) >> 3;
            int c = (lane & 7) ^ (r & 7);
            gl16(&Kh[(size_t)(kt * 64 + r) * 64 + c * 8], &lK[bufi][slot0 * 8]);
            gl16(&Vh[(size_t)r * 2048 + kt * 64 + c * 8], &lV[bufi][slot0 * 8]);
        }
    };

    // wave-private P rows: q = wave*32 + qh*16 + lm, 128 B per row
    char* lPr0 = (char*)lP + (wave * 32 + lm) * 128;
    char* lPr1 = lPr0 + 16 * 128;

    auto compute = [&](int cur) {
        // S^T = K * Q^T for both q-halves; kf loaded once, used twice
        floatx4 s[2][4];
#pragma unroll
        for (int qh = 0; qh < 2; qh++)
#pragma unroll
            for (int i = 0; i < 4; i++) s[qh][i] = (floatx4){0.f, 0.f, 0.f, 0.f};
        SETPRIO(1);
#pragma unroll
        for (int ns = 0; ns < 4; ns++) {
            int r = ns * 16 + lm;  // (r&7)==s7
            short8 kf0 = *(const short8*)&lK[cur][(r * 8 + (quad ^ s7)) * 8];
            short8 kf1 = *(const short8*)&lK[cur][(r * 8 + ((4 + quad) ^ s7)) * 8];
            s[0][ns] = MFMA16(kf0, qf[0][0], s[0][ns], 0, 0, 0);
            s[0][ns] = MFMA16(kf1, qf[0][1], s[0][ns], 0, 0, 0);
            s[1][ns] = MFMA16(kf0, qf[1][0], s[1][ns], 0, 0, 0);
            s[1][ns] = MFMA16(kf1, qf[1][1], s[1][ns], 0, 0, 0);
        }
        SETPRIO(0);

        // p = exp2(s); pack pairs; one b64 write per (qh, ns).
        // lane holds q=lm (within half), k = 16ns + 4quad + rr
#pragma unroll
        for (int qh = 0; qh < 2; qh++) {
            char* pr = qh ? lPr1 : lPr0;
#pragma unroll
            for (int ns = 0; ns < 4; ns++) {
                float p0 = __builtin_amdgcn_exp2f(s[qh][ns][0]);
                float p1 = __builtin_amdgcn_exp2f(s[qh][ns][1]);
                float p2 = __builtin_amdgcn_exp2f(s[qh][ns][2]);
                float p3 = __builtin_amdgcn_exp2f(s[qh][ns][3]);
                union { __hip_bfloat162 h2[2]; short4v s4; } pk;
                pk.h2[0] = __float22bfloat162_rn(make_float2(p0, p1));
                pk.h2[1] = __float22bfloat162_rn(make_float2(p2, p3));
                int sw = (2 * ns + (quad >> 1)) ^ s7;
                *(short4v*)(pr + sw * 16 + (quad & 1) * 8) = pk.s4;
            }
        }
        // no barrier: lP rows are wave-private, LDS ops in-order per wave

        // O += P * V;  accL += P * 1s.  vf loaded once, used for both halves.
        SETPRIO(1);
#pragma unroll
        for (int kk = 0; kk < 2; kk++) {
            int c2 = (kk * 4 + quad) ^ s7;
            short8 pf0 = *(const short8*)(lPr0 + c2 * 16);
            short8 pf1 = *(const short8*)(lPr1 + c2 * 16);
            accL[0] = MFMA16(pf0, onesf, accL[0], 0, 0, 0);
            accL[1] = MFMA16(pf1, onesf, accL[1], 0, 0, 0);
#pragma unroll
            for (int ns = 0; ns < 4; ns++) {
                int r = ns * 16 + lm;
                short8 vf = *(const short8*)&lV[cur][(r * 8 + ((kk * 4 + quad) ^ s7)) * 8];
                o[0][ns] = MFMA16(pf0, vf, o[0][ns], 0, 0, 0);
                o[1][ns] = MFMA16(pf1, vf, o[1][ns], 0, 0, 0);
            }
        }
        SETPRIO(0);
    };

    stage(0, 0);
    for (int kt = 0; kt < 31; kt++) {
        int cur = kt & 1;
        BARRIER();                      // all reads of buf cur^1 finished
        stage(cur ^ 1, kt + 1);         // 4 loads
        asm volatile("s_waitcnt vmcnt(4)" ::: "memory");
        BARRIER();                      // everyone's tile-kt loads done
        SCHEDB0();
        compute(cur);
    }
    BARRIER();
    asm volatile("s_waitcnt vmcnt(0)" ::: "memory");
    BARRIER();
    SCHEDB0();
    compute(1);  // kt=31

    float inv[2][4];
#pragma unroll
    for (int qh = 0; qh < 2; qh++)
#pragma unroll
        for (int rr = 0; rr < 4; rr++) inv[qh][rr] = 1.f / accL[qh][rr];

#pragma unroll
    for (int qh = 0; qh < 2; qh++) {
#pragma unroll
        for (int ns = 0; ns < 4; ns++) {
            int e = h * 64 + ns * 16 + lm;
#pragma unroll
            for (int rr = 0; rr < 4; rr++) {
                int srow = qt * 128 + wave * 32 + qh * 16 + quad * 4 + rr;
                ctx[(size_t)(b * 2048 + srow) * 1024 + e] =
                    __float2bfloat16(o[qh][ns][rr] * inv[qh][rr]);
            }
        }
    }
}

extern "C" void kernel_launch(void* const* d_in, const int* in_sizes, int n_in,
                              void* d_out, int out_size, void* d_ws, size_t ws_size,
                              hipStream_t stream) {
    const float* xv = (const float*)d_in[0];
    const float* xk = (const float*)d_in[1];
    const float* xq = (const float*)d_in[2];
    const float* Wq = (const float*)d_in[3];
    const float* bq = (const float*)d_in[4];
    const float* Wk = (const float*)d_in[5];
    const float* bk = (const float*)d_in[6];
    const float* Wv = (const float*)d_in[7];
    const float* bv = (const float*)d_in[8];
    const float* Wo = (const float*)d_in[9];
    const float* bo = (const float*)d_in[10];
    float* out = (float*)d_out;
    bf16* ws = (bf16*)d_ws;

    const size_t MB1 = 1024 * 1024;
    bf16* wt  = ws;              // 4 transposed bf16 weights (q,k,v,o)
    bf16* Qw  = ws + 4 * MB1;    // [B,H,S,D], pre-scaled by log2e/8
    bf16* Kw  = ws + 8 * MB1;    // [B,H,S,D]
    bf16* Vt  = ws + 12 * MB1;   // [B,H,D,S]
    bf16* ctx = ws + 16 * MB1;   // [B,S,E]
    bf16* xb  = ws + 20 * MB1;   // 3 bf16 activation tensors (q,k,v) (total 64 MB)

    hipLaunchKernelGGL(wtrans_k, dim3(32, 32, 4), dim3(32, 8), 0, stream,
                       Wq, Wk, Wv, Wo, wt);

    hipLaunchKernelGGL(xcast_k, dim3(2048, 3), dim3(256), 0, stream,
                       xq, xk, xv, xb);

    hipLaunchKernelGGL(qkv_k, dim3(32, 8, 3), dim3(256), 0, stream,
                       xb, wt, bq, bk, bv, Qw, Kw, Vt);

    hipLaunchKernelGGL(attn_k, dim3(32, 16), dim3(256), 0, stream, Qw, Kw, Vt, ctx);

    hipLaunchKernelGGL(outproj_k, dim3(32, 16), dim3(256), 0, stream,
                       ctx, wt + 3 * MB1, bo, out);
}

// Round 5
// 210.111 us; speedup vs baseline: 1.2159x; 1.0437x over previous
//
#include <hip/hip_runtime.h>
#include <hip/hip_bf16.h>

typedef __hip_bfloat16 bf16;
typedef __attribute__((ext_vector_type(8))) short short8;
typedef __attribute__((ext_vector_type(4))) short short4v;
typedef __attribute__((ext_vector_type(4))) float floatx4;

#define MFMA16 __builtin_amdgcn_mfma_f32_16x16x32_bf16
#define BARRIER __builtin_amdgcn_s_barrier
#define SCHEDB0() __builtin_amdgcn_sched_barrier(0)
#define SETPRIO __builtin_amdgcn_s_setprio

// ---------------------------------------------------------------------------
// B=2, S=2048, E=1024, H=16, D=64; M = 4096.  fp32 I/O, bf16 MFMA internal.
// R10 post-mortem: attn 56.6us; wall 4245cy/iter vs LDS floor 2635 ->
// P round-trip (8KB/wave/iter) + dependency chain exp->write->read->MFMA
// is the residual.  R11: 2x2 wave split (wq=q-half 64 rows, wk=k-half 32
// rows).  Swapped-QK C-frag (col=lm=q, row=quad*4+rr=k) IS the PV A-frag
// under slot map k=(j>>2)*16+quad*4+(j&3) -> P stays in registers, zero
// LDS round-trip.  V B-frag packs two b64 reads from [d][s] tile into the
// same slot map.  Per-wave LDS traffic 24KB -> 8KB/iter.  One-time
// cross-wave O/L reduction via retired K/V LDS (32KB) at end.
// ---------------------------------------------------------------------------

__device__ __forceinline__ void gl16(const void* g, void* l) {
    __builtin_amdgcn_global_load_lds(
        (const __attribute__((address_space(1))) void*)g,
        (__attribute__((address_space(3))) void*)l, 16, 0, 0);
}

// 4x fused 1024x1024 transpose + fp32->bf16: Wt[z][n][k] = (bf16)W[z][k][n]
__global__ __launch_bounds__(256) void wtrans_k(const float* __restrict__ w0,
                                                const float* __restrict__ w1,
                                                const float* __restrict__ w2,
                                                const float* __restrict__ w3,
                                                bf16* __restrict__ dst) {
    const float* srcs[4] = {w0, w1, w2, w3};
    const float* src = srcs[blockIdx.z];
    bf16* d = dst + (size_t)blockIdx.z * 1024 * 1024;
    __shared__ float t[32][33];
    int tx = threadIdx.x, ty = threadIdx.y;  // (32, 8)
    int x0 = blockIdx.x * 32, y0 = blockIdx.y * 32;
#pragma unroll
    for (int i = 0; i < 4; i++)
        t[ty + i * 8][tx] = src[(size_t)(y0 + ty + i * 8) * 1024 + x0 + tx];
    __syncthreads();
#pragma unroll
    for (int i = 0; i < 4; i++)
        d[(size_t)(x0 + ty + i * 8) * 1024 + y0 + tx] =
            __float2bfloat16(t[tx][ty + i * 8]);
}

// fp32 -> bf16 cast of the three activation tensors, 8 elems/thread.
__global__ __launch_bounds__(256) void xcast_k(const float* __restrict__ x0,
                                               const float* __restrict__ x1,
                                               const float* __restrict__ x2,
                                               bf16* __restrict__ dst) {
    const float* srcs[3] = {x0, x1, x2};
    const float* src = srcs[blockIdx.y];
    bf16* d = dst + (size_t)blockIdx.y * (4096 * 1024);
    size_t i = (size_t)blockIdx.x * 256 + threadIdx.x;  // 8-elem chunk index
    const float4* s4 = (const float4*)src + i * 2;
    float4 a = s4[0], b = s4[1];
    union { __hip_bfloat162 h2[4]; short8 s; } pk;
    pk.h2[0] = __float22bfloat162_rn(make_float2(a.x, a.y));
    pk.h2[1] = __float22bfloat162_rn(make_float2(a.z, a.w));
    pk.h2[2] = __float22bfloat162_rn(make_float2(b.x, b.y));
    pk.h2[3] = __float22bfloat162_rn(make_float2(b.z, b.w));
    *(short8*)&d[i * 8] = pk.s;
}

// Fused QKV projection, pure bf16, 128x128 tiles, BK=32, depth-2 prefetch
// (3 buffers, steady-state vmcnt(8): tiles kt+1,kt+2 in flight).
// Grid (32 m, 8 n, 3 z).  z=0: Q*(log2e/8); z=1: K; z=2: V -> [B,H,D,S].
__global__ __launch_bounds__(256) void qkv_k(const bf16* __restrict__ xb,
                                             const bf16* __restrict__ wt,
                                             const float* __restrict__ bq,
                                             const float* __restrict__ bk,
                                             const float* __restrict__ bv,
                                             bf16* __restrict__ Qw,
                                             bf16* __restrict__ Kw,
                                             bf16* __restrict__ Vt) {
    __shared__ __align__(16) bf16 lA[3][128 * 32];  // 3x8 KB, swizzled
    __shared__ __align__(16) bf16 lB[3][128 * 32];  // 3x8 KB, swizzled
    int z = blockIdx.z;
    const bf16* A = xb + (size_t)z * (4096 * 1024);
    const bf16* Bt = wt + (size_t)z * (1024 * 1024);
    const float* bias = (z == 0) ? bq : (z == 1) ? bk : bv;
    int m0 = blockIdx.x * 128, n0 = blockIdx.y * 128;
    int tid = threadIdx.x, wave = tid >> 6, lane = tid & 63;
    int lm = lane & 15, quad = lane >> 4;
    int wm = wave >> 1, wn = wave & 1;
    int swb = quad ^ ((lm >> 1) & 3);

    floatx4 acc[4][4];
#pragma unroll
    for (int i = 0; i < 4; i++)
#pragma unroll
        for (int j = 0; j < 4; j++) acc[i][j] = (floatx4){0.f, 0.f, 0.f, 0.f};

    auto stage = [&](int bufi, int kt) {
        // A and B bf16 tiles: 512 slots each, 2 gl16/wave each (4 loads total)
#pragma unroll
        for (int q2 = 0; q2 < 2; q2++) {
            int slot0 = wave * 128 + q2 * 64;
            int r = (slot0 + lane) >> 2;
            int c = (lane & 3) ^ ((r >> 1) & 3);
            gl16(&A[(size_t)(m0 + r) * 1024 + kt * 32 + c * 8],
                 &lA[bufi][slot0 * 8]);
            gl16(&Bt[(size_t)(n0 + r) * 1024 + kt * 32 + c * 8],
                 &lB[bufi][slot0 * 8]);
        }
    };

    auto compute = [&](int cur) {
        short8 af[4], bfr[4];
#pragma unroll
        for (int ms = 0; ms < 4; ms++) {
            int r = wm * 64 + ms * 16 + lm;  // ((r>>1)&3)==(lm>>1)&3
            af[ms] = *(const short8*)&lA[cur][(r * 4 + swb) * 8];
        }
#pragma unroll
        for (int ns = 0; ns < 4; ns++) {
            int r = wn * 64 + ns * 16 + lm;
            bfr[ns] = *(const short8*)&lB[cur][(r * 4 + swb) * 8];
        }
        SETPRIO(1);
#pragma unroll
        for (int ms = 0; ms < 4; ms++)
#pragma unroll
            for (int ns = 0; ns < 4; ns++)
                acc[ms][ns] = MFMA16(af[ms], bfr[ns], acc[ms][ns], 0, 0, 0);
        SETPRIO(0);
    };

    stage(0, 0);
    stage(1, 1);
    for (int kt = 0; kt < 32; kt++) {
        int cur = kt % 3;
        BARRIER();  // all reads of buf (kt+2)%3 (done at iter kt-1) finished
        if (kt < 30) {
            stage((kt + 2) % 3, kt + 2);
            asm volatile("s_waitcnt vmcnt(8)" ::: "memory");  // tile kt done
        } else if (kt == 30) {
            asm volatile("s_waitcnt vmcnt(4)" ::: "memory");
        } else {
            asm volatile("s_waitcnt vmcnt(0)" ::: "memory");
        }
        BARRIER();  // everyone's tile-kt loads done
        SCHEDB0();
        compute(cur);
    }

    bf16* dstQK = (z == 0) ? Qw : Kw;
    float scale = (z == 0) ? 0.125f * 1.44269504f : 1.0f;  // fold log2e for exp2
#pragma unroll
    for (int ms = 0; ms < 4; ms++) {
        int rowb = m0 + wm * 64 + ms * 16 + quad * 4;
        int bb = rowb >> 11, s0 = rowb & 2047;
#pragma unroll
        for (int ns = 0; ns < 4; ns++) {
            int col = n0 + wn * 64 + ns * 16 + lm;
            float bvv = bias[col];
            int hh = col >> 6, d = col & 63;
            if (z < 2) {
#pragma unroll
                for (int rr = 0; rr < 4; rr++) {
                    float v = (acc[ms][ns][rr] + bvv) * scale;
                    dstQK[((((size_t)bb * 16 + hh) * 2048 + s0 + rr) << 6) + d] =
                        __float2bfloat16(v);
                }
            } else {
                short4v pk;
#pragma unroll
                for (int rr = 0; rr < 4; rr++) {
                    bf16 h = __float2bfloat16(acc[ms][ns][rr] + bvv);
                    pk[rr] = *(short*)&h;
                }
                *(short4v*)&Vt[((((size_t)bb * 16 + hh) * 64 + d) << 11) + s0] = pk;
            }
        }
    }
}

// Output projection: ctx[4096][1024] bf16 @ Wo^T + bo -> fp32.  128x64 tiles,
// grid (32 m, 16 n), counted-vmcnt double-buffered staging (3 loads/wave).
__global__ __launch_bounds__(256) void outproj_k(const bf16* __restrict__ ctx,
                                                 const bf16* __restrict__ wot,
                                                 const float* __restrict__ bo,
                                                 float* __restrict__ out) {
    __shared__ __align__(16) bf16 lA[2][128 * 32];
    __shared__ __align__(16) bf16 lB[2][64 * 32];
    int m0 = blockIdx.x * 128, n0 = blockIdx.y * 64;
    int tid = threadIdx.x, wave = tid >> 6, lane = tid & 63;
    int lm = lane & 15, quad = lane >> 4;
    int wm = wave >> 1, wn = wave & 1;
    int swb = quad ^ ((lm >> 1) & 3);

    floatx4 acc[4][2];
#pragma unroll
    for (int i = 0; i < 4; i++)
#pragma unroll
        for (int j = 0; j < 2; j++) acc[i][j] = (floatx4){0.f, 0.f, 0.f, 0.f};

    auto stage = [&](int bufi, int kt) {
#pragma unroll
        for (int q2 = 0; q2 < 2; q2++) {
            int slot0 = wave * 128 + q2 * 64;
            int r = (slot0 + lane) >> 2;
            int c = (lane & 3) ^ ((r >> 1) & 3);
            gl16(&ctx[(size_t)(m0 + r) * 1024 + kt * 32 + c * 8],
                 &lA[bufi][slot0 * 8]);
        }
        {
            int slot0 = wave * 64;
            int r = (slot0 + lane) >> 2;
            int c = (lane & 3) ^ ((r >> 1) & 3);
            gl16(&wot[(size_t)(n0 + r) * 1024 + kt * 32 + c * 8],
                 &lB[bufi][slot0 * 8]);
        }
    };

    auto compute = [&](int cur) {
        short8 af[4], bfr[2];
#pragma unroll
        for (int ms = 0; ms < 4; ms++) {
            int r = wm * 64 + ms * 16 + lm;
            af[ms] = *(const short8*)&lA[cur][(r * 4 + swb) * 8];
        }
#pragma unroll
        for (int ns = 0; ns < 2; ns++) {
            int r = wn * 32 + ns * 16 + lm;
            bfr[ns] = *(const short8*)&lB[cur][(r * 4 + swb) * 8];
        }
        SETPRIO(1);
#pragma unroll
        for (int ms = 0; ms < 4; ms++)
#pragma unroll
            for (int ns = 0; ns < 2; ns++)
                acc[ms][ns] = MFMA16(af[ms], bfr[ns], acc[ms][ns], 0, 0, 0);
        SETPRIO(0);
    };

    stage(0, 0);
    for (int kt = 0; kt < 31; kt++) {
        int cur = kt & 1;
        BARRIER();
        stage(cur ^ 1, kt + 1);  // 3 loads
        asm volatile("s_waitcnt vmcnt(3)" ::: "memory");
        BARRIER();
        SCHEDB0();
        compute(cur);
    }
    BARRIER();
    asm volatile("s_waitcnt vmcnt(0)" ::: "memory");
    BARRIER();
    SCHEDB0();
    compute(1);  // kt=31

#pragma unroll
    for (int ms = 0; ms < 4; ms++) {
        int rowb = m0 + wm * 64 + ms * 16 + quad * 4;
#pragma unroll
        for (int ns = 0; ns < 2; ns++) {
            int col = n0 + wn * 32 + ns * 16 + lm;
            float bvv = bo[col];
#pragma unroll
            for (int rr = 0; rr < 4; rr++)
                out[(size_t)(rowb + rr) * 1024 + col] = acc[ms][ns][rr] + bvv;
        }
    }
}

// Flash attention, max-free softmax (|s| << 80), QBLK=128 / KVBLK=64.
// 2x2 wave split: wave (wq,wk) owns q in [wq*64,+64), k in [wk*32,+32).
// Q,K: [B,H,S,D] (Q pre-scaled by 0.125*log2e); Vt: [B,H,D,S].
// Grid (32 bh, 16 qtile), 256 thr, ~33KB LDS.
// Swapped QK^T: s = mfma(K,Q) = S^T, C-frag (col=lm=q, row=quad*4+rr=k_loc).
// In-register P: under MFMA slot map k = (j>>2)*16 + quad*4 + (j&3), the
// exp'd C-frag packs directly into the PV A-operand (pz short8); V B-frag
// packs two b64 reads from the [d][s] tile into the same slots.  Zero P
// LDS traffic.  Row sums via ones-MFMA.  Cross-wave (wk) O/L reduction
// once at the end through the retired K/V LDS.
__global__ __launch_bounds__(256, 2) void attn_k(const bf16* __restrict__ Q,
                                                 const bf16* __restrict__ K,
                                                 const bf16* __restrict__ Vt,
                                                 bf16* __restrict__ ctx) {
    __shared__ __align__(16) bf16 lKV[2][2][64 * 64];  // [K/V][buf] 32 KB
    __shared__ float scrL[2][64];
    int bh = blockIdx.x, qt = blockIdx.y;
    int b = bh >> 4, h = bh & 15;
    const bf16* Qh = Q + (size_t)bh * (2048 * 64);
    const bf16* Kh = K + (size_t)bh * (2048 * 64);
    const bf16* Vh = Vt + (size_t)bh * (64 * 2048);
    int tid = threadIdx.x, wave = tid >> 6, lane = tid & 63;
    int lm = lane & 15, quad = lane >> 4;
    int s7 = lm & 7;
    int wq = wave >> 1, wk = wave & 1;

    // Q B-frags for 4 q-blocks x 2 d-slices; q = qt*128 + wq*64 + qblk*16 + lm
    short8 qf[4][2];
#pragma unroll
    for (int qblk = 0; qblk < 4; qblk++) {
        int qrow = qt * 128 + wq * 64 + qblk * 16 + lm;
        qf[qblk][0] = *(const short8*)&Qh[(size_t)qrow * 64 + quad * 8];
        qf[qblk][1] = *(const short8*)&Qh[(size_t)qrow * 64 + 32 + quad * 8];
    }

    short8 onesf;
#pragma unroll
    for (int i = 0; i < 8; i++) onesf[i] = (short)0x3F80;  // bf16 1.0

    floatx4 o[4][4];  // [qblk][dblk]
#pragma unroll
    for (int i = 0; i < 4; i++)
#pragma unroll
        for (int j = 0; j < 4; j++) o[i][j] = (floatx4){0.f, 0.f, 0.f, 0.f};
    floatx4 accL[4];
#pragma unroll
    for (int i = 0; i < 4; i++) accL[i] = (floatx4){0.f, 0.f, 0.f, 0.f};

    auto stage = [&](int bufi, int kt) {
        // K (64 s-rows x 8 chunks) and V (64 d-rows x 8 chunks), c ^= r&7
#pragma unroll
        for (int q2 = 0; q2 < 2; q2++) {
            int slot0 = wave * 128 + q2 * 64;
            int r = (slot0 + lane) >> 3;
            int c = (lane & 7) ^ (r & 7);
            gl16(&Kh[(size_t)(kt * 64 + r) * 64 + c * 8], &lKV[0][bufi][slot0 * 8]);
            gl16(&Vh[(size_t)r * 2048 + kt * 64 + c * 8], &lKV[1][bufi][slot0 * 8]);
        }
    };

    auto compute = [&](int cur) {
        // --- QK^T: S^T[k_loc 32][q 64], wave's k rows = wk*32 + ksub*16 + lm
        short8 kf[2][2];
#pragma unroll
        for (int ksub = 0; ksub < 2; ksub++) {
            int r = wk * 32 + ksub * 16 + lm;  // (r&7)==s7
#pragma unroll
            for (int ds = 0; ds < 2; ds++)
                kf[ksub][ds] = *(const short8*)
                    &lKV[0][cur][(r * 8 + ((ds * 4 + quad) ^ s7)) * 8];
        }
        floatx4 s[4][2];
#pragma unroll
        for (int i = 0; i < 4; i++)
#pragma unroll
            for (int j = 0; j < 2; j++) s[i][j] = (floatx4){0.f, 0.f, 0.f, 0.f};
        SETPRIO(1);
#pragma unroll
        for (int qblk = 0; qblk < 4; qblk++)
#pragma unroll
            for (int ksub = 0; ksub < 2; ksub++) {
                s[qblk][ksub] = MFMA16(kf[ksub][0], qf[qblk][0], s[qblk][ksub], 0, 0, 0);
                s[qblk][ksub] = MFMA16(kf[ksub][1], qf[qblk][1], s[qblk][ksub], 0, 0, 0);
            }
        SETPRIO(0);

        // --- P = exp2(S^T), packed in-register into PV A-frags.
        // Lane holds q=lm, k_loc = ksub*16 + quad*4 + rr  ->  slot j = ksub*4+rr.
        short8 pz[4];
#pragma unroll
        for (int qblk = 0; qblk < 4; qblk++) {
            union { short4v h[2]; short8 s8; } up;
#pragma unroll
            for (int ksub = 0; ksub < 2; ksub++) {
                float p0 = __builtin_amdgcn_exp2f(s[qblk][ksub][0]);
                float p1 = __builtin_amdgcn_exp2f(s[qblk][ksub][1]);
                float p2 = __builtin_amdgcn_exp2f(s[qblk][ksub][2]);
                float p3 = __builtin_amdgcn_exp2f(s[qblk][ksub][3]);
                union { __hip_bfloat162 b2[2]; short4v s4; } c;
                c.b2[0] = __float22bfloat162_rn(make_float2(p0, p1));
                c.b2[1] = __float22bfloat162_rn(make_float2(p2, p3));
                up.h[ksub] = c.s4;
            }
            pz[qblk] = up.s8;
        }

        // --- V B-frags: lane needs V[k][d=dblk*16+lm] at k = wk*32 +
        // ksub*16 + quad*4 + {0..3} -> b64 from [d][s] tile, chunk
        // g = 4wk + 2ksub + (quad>>1), elem off (quad&1)*4, swizzle ^ s7.
        short8 vfz[4];
#pragma unroll
        for (int dblk = 0; dblk < 4; dblk++) {
            int d = dblk * 16 + lm;  // (d&7)==s7
            union { short4v h[2]; short8 s8; } uv;
#pragma unroll
            for (int ksub = 0; ksub < 2; ksub++) {
                int g = 4 * wk + 2 * ksub + (quad >> 1);
                uv.h[ksub] = *(const short4v*)
                    &lKV[1][cur][(d * 8 + (g ^ s7)) * 8 + (quad & 1) * 4];
            }
            vfz[dblk] = uv.s8;
        }

        // --- O += P*V;  accL += P*1 (row sums over this wave's 32 k)
        SETPRIO(1);
#pragma unroll
        for (int qblk = 0; qblk < 4; qblk++) {
            accL[qblk] = MFMA16(pz[qblk], onesf, accL[qblk], 0, 0, 0);
#pragma unroll
            for (int dblk = 0; dblk < 4; dblk++)
                o[qblk][dblk] = MFMA16(pz[qblk], vfz[dblk], o[qblk][dblk], 0, 0, 0);
        }
        SETPRIO(0);
    };

    stage(0, 0);
    for (int kt = 0; kt < 31; kt++) {
        int cur = kt & 1;
        BARRIER();                      // all reads of buf cur^1 finished
        stage(cur ^ 1, kt + 1);         // 4 loads
        asm volatile("s_waitcnt vmcnt(4)" ::: "memory");
        BARRIER();                      // everyone's tile-kt loads done
        SCHEDB0();
        compute(cur);
    }
    BARRIER();
    asm volatile("s_waitcnt vmcnt(0)" ::: "memory");
    BARRIER();
    SCHEDB0();
    compute(1);  // kt=31

    // --- cross-wave (wk) reduction of O and L via retired K/V LDS ---
    __syncthreads();  // all K/V reads done; safe to overwrite
    float* scrO = (float*)&lKV[0][0][0];  // [wq][q 64][d 64] fp32, 32 KB
    if (wk == 1) {
#pragma unroll
        for (int qblk = 0; qblk < 4; qblk++) {
#pragma unroll
            for (int dblk = 0; dblk < 4; dblk++)
#pragma unroll
                for (int rr = 0; rr < 4; rr++)
                    scrO[wq * 4096 + (qblk * 16 + quad * 4 + rr) * 64 +
                         dblk * 16 + lm] = o[qblk][dblk][rr];
#pragma unroll
            for (int rr = 0; rr < 4; rr++)
                scrL[wq][qblk * 16 + quad * 4 + rr] = accL[qblk][rr];
        }
    }
    __syncthreads();
    if (wk == 0) {
#pragma unroll
        for (int qblk = 0; qblk < 4; qblk++) {
            float inv[4];
#pragma unroll
            for (int rr = 0; rr < 4; rr++)
                inv[rr] = 1.f / (accL[qblk][rr] +
                                 scrL[wq][qblk * 16 + quad * 4 + rr]);
#pragma unroll
            for (int dblk = 0; dblk < 4; dblk++) {
                int e = h * 64 + dblk * 16 + lm;
#pragma unroll
                for (int rr = 0; rr < 4; rr++) {
                    int srow = qt * 128 + wq * 64 + qblk * 16 + quad * 4 + rr;
                    float of = o[qblk][dblk][rr] +
                               scrO[wq * 4096 + (qblk * 16 + quad * 4 + rr) * 64 +
                                    dblk * 16 + lm];
                    ctx[(size_t)(b * 2048 + srow) * 1024 + e] =
                        __float2bfloat16(of * inv[rr]);
                }
            }
        }
    }
}

extern "C" void kernel_launch(void* const* d_in, const int* in_sizes, int n_in,
                              void* d_out, int out_size, void* d_ws, size_t ws_size,
                              hipStream_t stream) {
    const float* xv = (const float*)d_in[0];
    const float* xk = (const float*)d_in[1];
    const float* xq = (const float*)d_in[2];
    const float* Wq = (const float*)d_in[3];
    const float* bq = (const float*)d_in[4];
    const float* Wk = (const float*)d_in[5];
    const float* bk = (const float*)d_in[6];
    const float* Wv = (const float*)d_in[7];
    const float* bv = (const float*)d_in[8];
    const float* Wo = (const float*)d_in[9];
    const float* bo = (const float*)d_in[10];
    float* out = (float*)d_out;
    bf16* ws = (bf16*)d_ws;

    const size_t MB1 = 1024 * 1024;
    bf16* wt  = ws;              // 4 transposed bf16 weights (q,k,v,o)
    bf16* Qw  = ws + 4 * MB1;    // [B,H,S,D], pre-scaled by log2e/8
    bf16* Kw  = ws + 8 * MB1;    // [B,H,S,D]
    bf16* Vt  = ws + 12 * MB1;   // [B,H,D,S]
    bf16* ctx = ws + 16 * MB1;   // [B,S,E]
    bf16* xb  = ws + 20 * MB1;   // 3 bf16 activation tensors (q,k,v) (total 64 MB)

    hipLaunchKernelGGL(wtrans_k, dim3(32, 32, 4), dim3(32, 8), 0, stream,
                       Wq, Wk, Wv, Wo, wt);

    hipLaunchKernelGGL(xcast_k, dim3(2048, 3), dim3(256), 0, stream,
                       xq, xk, xv, xb);

    hipLaunchKernelGGL(qkv_k, dim3(32, 8, 3), dim3(256), 0, stream,
                       xb, wt, bq, bk, bv, Qw, Kw, Vt);

    hipLaunchKernelGGL(attn_k, dim3(32, 16), dim3(256), 0, stream, Qw, Kw, Vt, ctx);

    hipLaunchKernelGGL(outproj_k, dim3(32, 16), dim3(256), 0, stream,
                       ctx, wt + 3 * MB1, bo, out);
}